// Round 11
// baseline (36215.222 us; speedup 1.0000x reference)
//
#include <hip/hip_runtime.h>
#include <cstdint>
#include <cstddef>

// ============================================================================
// VoiceCloningGenerator — R10 (green) + hot-spin barrier (anti-DVFS).
// All waves spin on the per-WG release flag with a dependent-FMA burn
// overlapping the poll load: chip stays busy -> clocks stay up.
// ============================================================================

#define DEVI __device__ __forceinline__

typedef short bf16x8 __attribute__((ext_vector_type(8)));
typedef float f32x4 __attribute__((ext_vector_type(4)));
typedef unsigned short u16x4 __attribute__((ext_vector_type(4)));

constexpr int B_ = 64, L_ = 512, T_ = 1000, E_ = 256, H_ = 512, M_ = 80, S_ = 128, Hd_ = 256;

DEVI unsigned short f2bs(float f) {
  unsigned u = __builtin_bit_cast(unsigned, f);
  unsigned r = u + 0x7fffu + ((u >> 16) & 1u);
  return (unsigned short)(r >> 16);
}
DEVI float b2f(unsigned short s) { return __builtin_bit_cast(float, (unsigned)s << 16); }
DEVI void split2(float v, unsigned short& hi, unsigned short& lo) {
  hi = f2bs(v);
  lo = f2bs(v - b2f(hi));
}
DEVI float sigm(float x) { x = fminf(fmaxf(x, -30.f), 30.f); return 1.f / (1.f + __expf(-x)); }
DEVI float tanh_(float x) { x = fminf(fmaxf(x, -15.f), 15.f); float e = __expf(2.f * x); return (e - 1.f) / (e + 1.f); }

DEVI f32x4 mfma16(bf16x8 a, bf16x8 b, f32x4 c) {
  return __builtin_amdgcn_mfma_f32_16x16x32_bf16(a, b, c, 0, 0, 0);
}

// --- asm memory ops (all pipeline loads are asm so vmcnt counts are exact) --
DEVI void ldg16(bf16x8& r, const unsigned short* p) {  // cached (L1/L2)
  asm volatile("global_load_dwordx4 %0, %1, off" : "=v"(r) : "v"(p));
}
DEVI void ldc16(bf16x8& r, const unsigned short* p) {  // coherence point
  asm volatile("global_load_dwordx4 %0, %1, off sc0 sc1" : "=v"(r) : "v"(p));
}
DEVI void st4c(unsigned short* p, unsigned v) {
  asm volatile("global_store_dword %0, %1, off sc0 sc1" :: "v"(p), "v"(v));
}
DEVI void sti4c(int* p, int v) {
  asm volatile("global_store_dword %0, %1, off sc0 sc1" :: "v"(p), "v"(v));
}
DEVI void st8c(unsigned short* p, u16x4 v) {
  asm volatile("global_store_dwordx2 %0, %1, off sc0 sc1" :: "v"(p), "v"(v));
}
#define WAITV(N) do { asm volatile("s_waitcnt vmcnt(" #N ")" ::: "memory"); \
                      __builtin_amdgcn_sched_barrier(0); } while (0)
#define VM_DRAIN() WAITV(0)

// --- hot-spin wait: poll load overlapped with dependent-FMA burn -----------
DEVI void hotwait(const int* p, int target) {
  int v;
  for (;;) {
    asm volatile("global_load_dword %0, %1, off sc0 sc1" : "=v"(v) : "v"(p));
    float x = 0.5f;
#pragma unroll
    for (int i = 0; i < 192; ++i)
      asm volatile("v_fmac_f32 %0, %1, %1" : "+v"(x) : "v"(x));
    asm volatile("" :: "v"(x));
    asm volatile("s_waitcnt vmcnt(0)" ::: "memory");
    __builtin_amdgcn_sched_barrier(0);
    if (v >= target) break;
  }
}

// --- barrier: arrive tree + per-WG release flag lines; all-wave hot poll ---
struct Bar { int sub[16][16]; int master[16]; int rel[128][16]; };

template <int NWG, int NSUB>
DEVI void grid_barX(Bar* bb, int step) {
  __shared__ int finS;
  const int tid = threadIdx.x;
  __syncthreads();
  if (tid == 0) {
    finS = 0;
    constexpr int per = NWG / NSUB;
    int old = __hip_atomic_fetch_add(&bb->sub[(int)blockIdx.x % NSUB][0], 1,
                                     __ATOMIC_RELAXED, __HIP_MEMORY_SCOPE_AGENT);
    if (old == per * (step + 1) - 1) {
      int om = __hip_atomic_fetch_add(&bb->master[0], 1,
                                      __ATOMIC_RELAXED, __HIP_MEMORY_SCOPE_AGENT);
      if (om == NSUB * (step + 1) - 1) finS = 1;
    }
  }
  __syncthreads();
  if (finS && tid < NWG) sti4c(&bb->rel[tid][0], step + 1);   // 1 line per WG
  hotwait(&bb->rel[(int)blockIdx.x][0], step + 1);            // all waves, hot
}

// --- 3-deep pipelined load/MFMA loop; batch = 8 asm loads ------------------
template <int N, class FI, class FM>
DEVI void pipe3(FI issue, FM domf) {
  bf16x8 S0[8], S1[8], S2[8];
  issue(0, S0);
  if constexpr (N > 1) issue(1, S1);
  if constexpr (N > 2) issue(2, S2);
#pragma unroll
  for (int j = 0; j < N; ++j) {
    if (j + 2 < N) { WAITV(16); } else if (j + 1 < N) { WAITV(8); } else { WAITV(0); }
    if (j % 3 == 0)      { domf(j, S0); if (j + 3 < N) issue(j + 3, S0); }
    else if (j % 3 == 1) { domf(j, S1); if (j + 3 < N) issue(j + 3, S1); }
    else                 { domf(j, S2); if (j + 3 < N) issue(j + 3, S2); }
  }
}

// ---------------------------------------------------------------------------
__global__ void k_prep(const float* __restrict__ embed, const float* __restrict__ tmel,
                       const float* __restrict__ mw1, const float* __restrict__ mw2,
                       unsigned short* emb_h, unsigned short* emb_l,
                       unsigned short* mel_h, unsigned short* mel_l,
                       unsigned short* w1_bf, unsigned short* w2_bf) {
  const long long stride = (long long)gridDim.x * blockDim.x;
  const long long i0 = (long long)blockIdx.x * blockDim.x + threadIdx.x;
  for (long long i = i0; i < 256 * 256; i += stride) {
    unsigned short h, l; split2(embed[i], h, l);
    emb_h[i] = h; emb_l[i] = l;
  }
  for (long long i = i0; i < (long long)T_ * B_ * 96; i += stride) {
    int c = (int)(i % 96);
    long long tb = i / 96;
    int b = (int)(tb % B_);
    int t = (int)(tb / B_);
    float v = 0.f;
    if (t > 0 && c < 80) v = tmel[((long long)b * T_ + (t - 1)) * M_ + c];
    unsigned short h, l; split2(v, h, l);
    mel_h[i] = h; mel_l[i] = l;
  }
  for (long long i = i0; i < 512 * 512; i += stride) w1_bf[i] = f2bs(mw1[i]);
  for (long long i = i0; i < 80 * 512; i += stride) w2_bf[i] = f2bs(mw2[i]);
}

// ---------------------------------------------------------------------------
__global__ void __launch_bounds__(512) k_sp(const float* __restrict__ spk,
                                            const float* __restrict__ w1, const float* __restrict__ b1,
                                            const float* __restrict__ w2, const float* __restrict__ b2,
                                            float* sp) {
  __shared__ float t1[512];
  const int b = blockIdx.x, j = threadIdx.x;
  float a = b1[j];
  const float* sr = spk + b * S_;
  for (int k = 0; k < S_; ++k) a += sr[k] * w1[j * S_ + k];
  t1[j] = fmaxf(a, 0.f);
  __syncthreads();
  float a2 = b2[j];
  for (int k = 0; k < H_; ++k) a2 += t1[k] * w2[j * H_ + k];
  sp[b * H_ + j] = a2;
}

// ---------------------------------------------------------------------------
// Encoder: 2 dirs x 16 WGs x 16 cols. Unified 4-batch pipeline per wave
// (kb = wv+4j: kb<8 embed cached, else h frag IC). enc_out written t-major.
// ---------------------------------------------------------------------------
constexpr int ENC_LDS = 2 * 16 * 4 * 64 * 16 + 4 * 64 * 16 * 4 + 256;  // 147712

__global__ void __launch_bounds__(256, 1) k_enc(
    const int* __restrict__ text,
    const float* __restrict__ WihF, const float* __restrict__ WhhF, const float* __restrict__ bF,
    const float* __restrict__ WihB, const float* __restrict__ WhhB, const float* __restrict__ bB,
    const unsigned short* __restrict__ emb_h, const unsigned short* __restrict__ emb_l,
    const float* __restrict__ sp,
    unsigned short* hencfh, unsigned short* hencfl,
    unsigned short* ench, unsigned short* encl, Bar* bar) {
  extern __shared__ char lds[];
  unsigned short* Wh = (unsigned short*)lds;
  unsigned short* Wl = Wh + 16 * 4 * 64 * 8;
  float* G = (float*)(lds + 2 * 16 * 4 * 64 * 16);
  float* bias = G + 4 * 64 * 16;

  const int wg = blockIdx.x;
  const int dir = wg >> 4;
  const int jhb = (wg & 15) * 16;
  const int tid = threadIdx.x;
  const int wv = tid >> 6, ln = tid & 63, lg = ln >> 4, lr = ln & 15;

  const float* Wih = dir ? WihB : WihF;
  const float* Whh = dir ? WhhB : WhhF;
  const float* bb = dir ? bB : bF;

  for (int s = tid; s < 16 * 4 * 64; s += 256) {
    int kb = s >> 8, g = (s >> 6) & 3, l = s & 63;
    int R = g * Hd_ + jhb + (l & 15);
    int k0 = kb * 32 + (l >> 4) * 8;
    const float* src = (k0 < E_) ? (Wih + (size_t)R * E_ + k0) : (Whh + (size_t)R * Hd_ + (k0 - E_));
    bf16x8 vh, vl;
#pragma unroll
    for (int j = 0; j < 8; ++j) {
      unsigned short a, b; split2(src[j], a, b);
      vh[j] = (short)a; vl[j] = (short)b;
    }
    *(bf16x8*)(Wh + (size_t)s * 8) = vh;
    *(bf16x8*)(Wl + (size_t)s * 8) = vl;
  }
  if (tid < 64) bias[tid] = bb[(tid >> 4) * Hd_ + jhb + (tid & 15)];

  const int eb = tid >> 2, ej0 = (tid & 3) * 4;
  float c4[4] = {0.f, 0.f, 0.f, 0.f};
  float spv[4];
#pragma unroll
  for (int q = 0; q < 4; ++q) spv[q] = sp[eb * H_ + dir * Hd_ + jhb + ej0 + q];

  const int jh = jhb + ej0;
  const size_t fro = ((size_t)((jh >> 5) * 4 + (eb >> 4)) * 64 +
                      (((jh >> 3) & 3) * 16 + (eb & 15))) * 8 + (jh & 7);

  __syncthreads();

  for (int t = 0; t < L_; ++t) {
    const int tpos = dir ? (L_ - 1 - t) : t;
    const unsigned short* hsh = hencfh + ((size_t)((t & 1) * 2 + dir)) * 16384;
    const unsigned short* hsl = hencfl + ((size_t)((t & 1) * 2 + dir)) * 16384;
    unsigned short* hdh = hencfh + ((size_t)(((t + 1) & 1) * 2 + dir)) * 16384;
    unsigned short* hdl = hencfl + ((size_t)(((t + 1) & 1) * 2 + dir)) * 16384;

    for (int i = tid; i < 4096; i += 256) G[i] = bias[((i >> 10) << 4) + (i & 15)];

    int tix[4];
#pragma unroll
    for (int m = 0; m < 4; ++m) tix[m] = text[(16 * m + lr) * L_ + tpos];

    f32x4 acc[4][4];
#pragma unroll
    for (int g = 0; g < 4; ++g)
#pragma unroll
      for (int m = 0; m < 4; ++m) acc[g][m] = (f32x4){0.f, 0.f, 0.f, 0.f};

    auto issue = [&](int j, bf16x8 (&S)[8]) {
      const int kb = wv + 4 * j;
      if (kb < 8) {
        const int k0 = kb * 32 + lg * 8;
#pragma unroll
        for (int m = 0; m < 4; ++m) {
          ldg16(S[m],     emb_h + (size_t)tix[m] * E_ + k0);
          ldg16(S[4 + m], emb_l + (size_t)tix[m] * E_ + k0);
        }
      } else {
        const unsigned short* ph = hsh + ((size_t)((kb - 8) * 4) * 64 + ln) * 8;
        const unsigned short* pl = hsl + ((size_t)((kb - 8) * 4) * 64 + ln) * 8;
#pragma unroll
        for (int m = 0; m < 4; ++m) { ldc16(S[m], ph + m * 512); ldc16(S[4 + m], pl + m * 512); }
      }
    };
    auto domf = [&](int j, bf16x8 (&S)[8]) {
      const int kb = wv + 4 * j;
#pragma unroll
      for (int g = 0; g < 4; ++g) {
        bf16x8 bh = *(bf16x8*)(Wh + ((size_t)(kb * 4 + g) * 64 + ln) * 8);
        bf16x8 bl = *(bf16x8*)(Wl + ((size_t)(kb * 4 + g) * 64 + ln) * 8);
#pragma unroll
        for (int m = 0; m < 4; ++m) {
          acc[g][m] = mfma16(S[m],     bh, acc[g][m]);
          acc[g][m] = mfma16(S[4 + m], bh, acc[g][m]);
          acc[g][m] = mfma16(S[m],     bl, acc[g][m]);
        }
      }
    };
    pipe3<4>(issue, domf);

    __syncthreads();
#pragma unroll
    for (int g = 0; g < 4; ++g)
#pragma unroll
      for (int m = 0; m < 4; ++m)
#pragma unroll
        for (int r = 0; r < 4; ++r)
          atomicAdd(&G[(g * 64 + 16 * m + 4 * lg + r) * 16 + lr], acc[g][m][r]);
    __syncthreads();

    {
      u16x4 hvh, hvl, ovh, ovl;
#pragma unroll
      for (int q = 0; q < 4; ++q) {
        int jj = ej0 + q;
        float gi = G[(0 * 64 + eb) * 16 + jj];
        float gf = G[(1 * 64 + eb) * 16 + jj];
        float gg = G[(2 * 64 + eb) * 16 + jj];
        float go = G[(3 * 64 + eb) * 16 + jj];
        float cn = sigm(gf) * c4[q] + sigm(gi) * tanh_(gg);
        c4[q] = cn;
        float h = sigm(go) * tanh_(cn);
        unsigned short a, b; split2(h, a, b);
        hvh[q] = a; hvl[q] = b;
        float o = h + spv[q];
        split2(o, a, b);
        ovh[q] = a; ovl[q] = b;
      }
      st8c(hdh + fro, hvh);
      st8c(hdl + fro, hvl);
      // t-major enc_out: [t][B][H]
      *(u16x4*)(ench + ((size_t)tpos * B_ + eb) * H_ + dir * Hd_ + jhb + ej0) = ovh;
      *(u16x4*)(encl + ((size_t)tpos * B_ + eb) * H_ + dir * Hd_ + jhb + ej0) = ovl;
    }
    VM_DRAIN();
    grid_barX<32, 8>(bar, t);
  }
}

// ---------------------------------------------------------------------------
// Decoder: 128 WGs (64/layer, 8 cols each), pipelined by one tick.
// Unified per-wave pipelines: L0 kb=wv+4j over 35 kbs, L1 over 32 kbs.
// ---------------------------------------------------------------------------
constexpr int DEC_LDS = 2 * 35 * 2 * 64 * 16 + 4 * 64 * 8 * 4 + 128;  // 151680

__global__ void __launch_bounds__(256, 1) k_dec(
    const float* __restrict__ Wih0, const float* __restrict__ Whh0, const float* __restrict__ b0,
    const float* __restrict__ Wih1, const float* __restrict__ Whh1, const float* __restrict__ b1,
    const unsigned short* __restrict__ ench, const unsigned short* __restrict__ encl,
    const unsigned short* __restrict__ melh, const unsigned short* __restrict__ mell,
    unsigned short* h0fh, unsigned short* h0fl,
    unsigned short* h1fh, unsigned short* h1fl,
    unsigned short* h2_full, Bar* bar) {
  extern __shared__ char lds[];
  const int wg = blockIdx.x;
  const int layer = wg >> 6;
  const int jcb = (wg & 63) * 8;
  const int tid = threadIdx.x, wv = tid >> 6, ln = tid & 63, lg = ln >> 4, lr = ln & 15;
  const int NKB = layer ? 32 : 35;
  unsigned short* Wh = (unsigned short*)lds;
  unsigned short* Wl = Wh + (size_t)NKB * 2 * 64 * 8;
  float* G = (float*)(lds + (size_t)2 * NKB * 2 * 64 * 16);
  float* bias = G + 4 * 64 * 8;

  if (layer == 0) {
    for (int s = tid; s < 35 * 2 * 64; s += 256) {
      int kb = s >> 7, st = (s >> 6) & 1, l = s & 63;
      int n = l & 15;
      int R = (2 * st + (n >> 3)) * H_ + jcb + (n & 7);
      int k0 = kb * 32 + (l >> 4) * 8;
      bf16x8 vh, vl;
      if (k0 < 96) {
#pragma unroll
        for (int j = 0; j < 8; ++j) {
          int c = k0 + j;
          float v = (c < 80) ? Wih0[(size_t)R * 592 + c] : 0.f;
          unsigned short a, b; split2(v, a, b);
          vh[j] = (short)a; vl[j] = (short)b;
        }
      } else if (k0 < 608) {
        const float* src = Wih0 + (size_t)R * 592 + (k0 - 16);
#pragma unroll
        for (int j = 0; j < 8; ++j) {
          unsigned short a, b; split2(src[j], a, b);
          vh[j] = (short)a; vl[j] = (short)b;
        }
      } else {
        const float* src = Whh0 + (size_t)R * H_ + (k0 - 608);
#pragma unroll
        for (int j = 0; j < 8; ++j) {
          unsigned short a, b; split2(src[j], a, b);
          vh[j] = (short)a; vl[j] = (short)b;
        }
      }
      *(bf16x8*)(Wh + (size_t)s * 8) = vh;
      *(bf16x8*)(Wl + (size_t)s * 8) = vl;
    }
    if (tid < 32) bias[tid] = b0[(tid >> 3) * H_ + jcb + (tid & 7)];
  } else {
    for (int s = tid; s < 32 * 2 * 64; s += 256) {
      int kb = s >> 7, st = (s >> 6) & 1, l = s & 63;
      int n = l & 15;
      int R = (2 * st + (n >> 3)) * H_ + jcb + (n & 7);
      int k0 = kb * 32 + (l >> 4) * 8;
      const float* src = (k0 < 512) ? (Wih1 + (size_t)R * H_ + k0) : (Whh1 + (size_t)R * H_ + (k0 - 512));
      bf16x8 vh, vl;
#pragma unroll
      for (int j = 0; j < 8; ++j) {
        unsigned short a, b; split2(src[j], a, b);
        vh[j] = (short)a; vl[j] = (short)b;
      }
      *(bf16x8*)(Wh + (size_t)s * 8) = vh;
      *(bf16x8*)(Wl + (size_t)s * 8) = vl;
    }
    if (tid < 32) bias[tid] = b1[(tid >> 3) * H_ + jcb + (tid & 7)];
  }

  const int ebd = tid & 63, cc0 = (tid >> 6) * 2;
  float c2[2] = {0.f, 0.f};
  const int j0w = jcb + cc0;
  const size_t frw = ((size_t)((j0w >> 5) * 4 + (ebd >> 4)) * 64 +
                      (((j0w >> 3) & 3) * 16 + (ebd & 15))) * 8 + (j0w & 7);
  __syncthreads();

  for (int tau = 0; tau <= T_; ++tau) {
    const bool active = (layer == 0) ? (tau < T_) : (tau >= 1);
    if (active) {
      const int t = (layer == 0) ? tau : tau - 1;
      for (int i = tid; i < 2048; i += 256) G[i] = bias[((i >> 9) << 3) + (i & 7)];

      f32x4 acc[2][4];
#pragma unroll
      for (int st = 0; st < 2; ++st)
#pragma unroll
        for (int m = 0; m < 4; ++m) acc[st][m] = (f32x4){0.f, 0.f, 0.f, 0.f};

      auto MF = [&](int kb, bf16x8 (&S)[8]) {
#pragma unroll
        for (int st = 0; st < 2; ++st) {
          bf16x8 bh = *(bf16x8*)(Wh + ((size_t)(kb * 2 + st) * 64 + ln) * 8);
          bf16x8 bl = *(bf16x8*)(Wl + ((size_t)(kb * 2 + st) * 64 + ln) * 8);
#pragma unroll
          for (int m = 0; m < 4; ++m) {
            acc[st][m] = mfma16(S[m],     bh, acc[st][m]);
            acc[st][m] = mfma16(S[4 + m], bh, acc[st][m]);
            acc[st][m] = mfma16(S[m],     bl, acc[st][m]);
          }
        }
      };

      if (layer == 0) {
        const int tq = t & (L_ - 1);
        const unsigned short* p0h = h0fh + (size_t)((tau + 1) & 1) * 32768;
        const unsigned short* p0l = h0fl + (size_t)((tau + 1) & 1) * 32768;
        auto issue = [&](int j, bf16x8 (&S)[8]) {
          const int kb = wv + 4 * j;
          const int k0 = kb * 32 + lg * 8;
          if (kb < 3) {
#pragma unroll
            for (int m = 0; m < 4; ++m) {
              ldg16(S[m],     melh + ((size_t)t * B_ + 16 * m + lr) * 96 + k0);
              ldg16(S[4 + m], mell + ((size_t)t * B_ + 16 * m + lr) * 96 + k0);
            }
          } else if (kb < 19) {
            const int k = k0 - 96;
#pragma unroll
            for (int m = 0; m < 4; ++m) {
              ldg16(S[m],     ench + ((size_t)tq * B_ + 16 * m + lr) * H_ + k);  // t-major
              ldg16(S[4 + m], encl + ((size_t)tq * B_ + 16 * m + lr) * H_ + k);
            }
          } else {
            const unsigned short* ph = p0h + ((size_t)((kb - 19) * 4) * 64 + ln) * 8;
            const unsigned short* pl = p0l + ((size_t)((kb - 19) * 4) * 64 + ln) * 8;
#pragma unroll
            for (int m = 0; m < 4; ++m) { ldc16(S[m], ph + m * 512); ldc16(S[4 + m], pl + m * 512); }
          }
        };
        auto domf = [&](int j, bf16x8 (&S)[8]) { MF(wv + 4 * j, S); };
        if (wv < 3) pipe3<9>(issue, domf);
        else        pipe3<8>(issue, domf);
      } else {
        const unsigned short* q0h = h0fh + (size_t)((tau + 1) & 1) * 32768;
        const unsigned short* q0l = h0fl + (size_t)((tau + 1) & 1) * 32768;
        const unsigned short* q1h = h1fh + (size_t)(tau & 1) * 32768;
        const unsigned short* q1l = h1fl + (size_t)(tau & 1) * 32768;
        auto issue = [&](int j, bf16x8 (&S)[8]) {
          const int kb = wv + 4 * j;
          const unsigned short* ph = (kb < 16) ? (q0h + ((size_t)(kb * 4) * 64 + ln) * 8)
                                               : (q1h + ((size_t)((kb - 16) * 4) * 64 + ln) * 8);
          const unsigned short* pl = (kb < 16) ? (q0l + ((size_t)(kb * 4) * 64 + ln) * 8)
                                               : (q1l + ((size_t)((kb - 16) * 4) * 64 + ln) * 8);
#pragma unroll
          for (int m = 0; m < 4; ++m) { ldc16(S[m], ph + m * 512); ldc16(S[4 + m], pl + m * 512); }
        };
        auto domf = [&](int j, bf16x8 (&S)[8]) { MF(wv + 4 * j, S); };
        pipe3<8>(issue, domf);
      }

      __syncthreads();
#pragma unroll
      for (int st = 0; st < 2; ++st)
#pragma unroll
        for (int m = 0; m < 4; ++m)
#pragma unroll
          for (int r = 0; r < 4; ++r) {
            int g = 2 * st + (lr >> 3), col = lr & 7;
            atomicAdd(&G[(g * 64 + 16 * m + 4 * lg + r) * 8 + col], acc[st][m][r]);
          }
      __syncthreads();

      {
        unsigned short* dh = layer ? (h1fh + (size_t)((tau + 1) & 1) * 32768)
                                   : (h0fh + (size_t)(tau & 1) * 32768);
        unsigned short* dl = layer ? (h1fl + (size_t)((tau + 1) & 1) * 32768)
                                   : (h0fl + (size_t)(tau & 1) * 32768);
        unsigned short hh[2], hl[2];
#pragma unroll
        for (int q = 0; q < 2; ++q) {
          int c = cc0 + q;
          float gi = G[(0 * 64 + ebd) * 8 + c];
          float gf = G[(1 * 64 + ebd) * 8 + c];
          float gg = G[(2 * 64 + ebd) * 8 + c];
          float go = G[(3 * 64 + ebd) * 8 + c];
          float cn = sigm(gf) * c2[q] + sigm(gi) * tanh_(gg);
          c2[q] = cn;
          float h = sigm(go) * tanh_(cn);
          split2(h, hh[q], hl[q]);
        }
        unsigned ph = (unsigned)hh[0] | ((unsigned)hh[1] << 16);
        unsigned pl = (unsigned)hl[0] | ((unsigned)hl[1] << 16);
        st4c(dh + frw, ph);
        st4c(dl + frw, pl);
        if (layer) *(unsigned*)(h2_full + ((size_t)t * B_ + ebd) * H_ + jcb + cc0) = ph;
      }
      VM_DRAIN();
    }
    grid_barX<128, 16>(bar, tau);
  }
}

// ---------------------------------------------------------------------------
constexpr int MLP_LDS = 64 * 1024;

__global__ void __launch_bounds__(256) k_mlp(
    const unsigned short* __restrict__ h2_full,
    const unsigned short* __restrict__ w1_bf, const unsigned short* __restrict__ w2_bf,
    const float* __restrict__ mb1, const float* __restrict__ mb2,
    const float* __restrict__ stW, const float* __restrict__ stb, float* out) {
  extern __shared__ char lds[];
  const int t = blockIdx.x;
  const int tid = threadIdx.x, wv = tid >> 6, ln = tid & 63, lg = ln >> 4, lr = ln & 15;
  const unsigned short* A = h2_full + (size_t)t * B_ * H_;

  for (int half = 0; half < 2; ++half) {
    const int nb = wv * 8 + half * 4;
    f32x4 acc[4][4];
#pragma unroll
    for (int nn = 0; nn < 4; ++nn) {
      float bv = mb1[(nb + nn) * 16 + lr];
#pragma unroll
      for (int m = 0; m < 4; ++m) acc[m][nn] = (f32x4){bv, bv, bv, bv};
    }
    for (int kb = 0; kb < 16; ++kb) {
      int k0 = kb * 32 + lg * 8;
      bf16x8 afr[4], bfr[4];
#pragma unroll
      for (int m = 0; m < 4; ++m) afr[m] = *(const bf16x8*)(A + (size_t)(16 * m + lr) * H_ + k0);
#pragma unroll
      for (int nn = 0; nn < 4; ++nn) bfr[nn] = *(const bf16x8*)(w1_bf + (size_t)((nb + nn) * 16 + lr) * H_ + k0);
#pragma unroll
      for (int m = 0; m < 4; ++m)
#pragma unroll
        for (int nn = 0; nn < 4; ++nn) acc[m][nn] = mfma16(afr[m], bfr[nn], acc[m][nn]);
    }
#pragma unroll
    for (int m = 0; m < 4; ++m)
#pragma unroll
      for (int nn = 0; nn < 4; ++nn)
#pragma unroll
        for (int r = 0; r < 4; ++r) {
          int row = 16 * m + 4 * lg + r, col = (nb + nn) * 16 + lr;
          *(unsigned short*)(lds + row * 1024 + ((col * 2) ^ ((row & 7) << 4))) =
              f2bs(fmaxf(acc[m][nn][r], 0.f));
        }
  }
  __syncthreads();

  {
    f32x4 acc2[5];
#pragma unroll
    for (int n = 0; n < 5; ++n) {
      float bv = mb2[n * 16 + lr];
      acc2[n] = (f32x4){bv, bv, bv, bv};
    }
    for (int kb = 0; kb < 16; ++kb) {
      int k0 = kb * 32 + lg * 8;
      int row = 16 * wv + lr;
      bf16x8 afr = *(bf16x8*)(lds + row * 1024 + ((k0 * 2) ^ ((row & 7) << 4)));
#pragma unroll
      for (int n = 0; n < 5; ++n) {
        bf16x8 bfr = *(const bf16x8*)(w2_bf + (size_t)(n * 16 + lr) * H_ + k0);
        acc2[n] = mfma16(afr, bfr, acc2[n]);
      }
    }
#pragma unroll
    for (int n = 0; n < 5; ++n)
#pragma unroll
      for (int r = 0; r < 4; ++r) {
        int b = 16 * wv + 4 * lg + r;
        out[((size_t)b * T_ + t) * M_ + n * 16 + lr] = acc2[n][r];
      }
  }

  if (tid < 64) {
    int b = tid;
    float s = stb[0];
    const unsigned short* hp = A + (size_t)b * H_;
    for (int k = 0; k < H_; ++k) s += b2f(hp[k]) * stW[k];
    out[(size_t)B_ * T_ * M_ + (size_t)b * T_ + t] = s;
  }
}

// ---------------------------------------------------------------------------
extern "C" void kernel_launch(void* const* d_in, const int* in_sizes, int n_in,
                              void* d_out, int out_size, void* d_ws, size_t ws_size,
                              hipStream_t stream) {
  (void)in_sizes; (void)n_in; (void)out_size; (void)ws_size;
  const int* text = (const int*)d_in[0];
  const float* spk = (const float*)d_in[1];
  const float* tmel = (const float*)d_in[2];
  const float* embed = (const float*)d_in[3];
  const float* eWihF = (const float*)d_in[4];
  const float* eWhhF = (const float*)d_in[5];
  const float* ebF = (const float*)d_in[6];
  const float* eWihB = (const float*)d_in[7];
  const float* eWhhB = (const float*)d_in[8];
  const float* ebB = (const float*)d_in[9];
  const float* spW1 = (const float*)d_in[10];
  const float* spb1 = (const float*)d_in[11];
  const float* spW2 = (const float*)d_in[12];
  const float* spb2 = (const float*)d_in[13];
  const float* dWih0 = (const float*)d_in[14];
  const float* dWhh0 = (const float*)d_in[15];
  const float* db0 = (const float*)d_in[16];
  const float* dWih1 = (const float*)d_in[17];
  const float* dWhh1 = (const float*)d_in[18];
  const float* db1 = (const float*)d_in[19];
  const float* mW1 = (const float*)d_in[20];
  const float* mb1 = (const float*)d_in[21];
  const float* mW2 = (const float*)d_in[22];
  const float* mb2 = (const float*)d_in[23];
  const float* stW = (const float*)d_in[24];
  const float* stb = (const float*)d_in[25];
  float* out = (float*)d_out;

  char* base = (char*)d_ws;
  size_t off = 0;
  auto carve = [&](size_t bytes) -> void* {
    void* p = base + off;
    off += (bytes + 255) & ~(size_t)255;
    return p;
  };
  // --- state region (zeroed each call) ---
  Bar* barE = (Bar*)carve(sizeof(Bar));
  Bar* barD = (Bar*)carve(sizeof(Bar));
  unsigned short* h0fh = (unsigned short*)carve((size_t)2 * 32768 * 2);
  unsigned short* h0fl = (unsigned short*)carve((size_t)2 * 32768 * 2);
  unsigned short* h1fh = (unsigned short*)carve((size_t)2 * 32768 * 2);
  unsigned short* h1fl = (unsigned short*)carve((size_t)2 * 32768 * 2);
  unsigned short* hencfh = (unsigned short*)carve((size_t)4 * 16384 * 2);
  unsigned short* hencfl = (unsigned short*)carve((size_t)4 * 16384 * 2);
  const size_t state_bytes = off;
  // --- write-before-read buffers ---
  float* sp = (float*)carve((size_t)B_ * H_ * 4);
  unsigned short* emb_h = (unsigned short*)carve((size_t)256 * 256 * 2);
  unsigned short* emb_l = (unsigned short*)carve((size_t)256 * 256 * 2);
  unsigned short* mel_h = (unsigned short*)carve((size_t)T_ * B_ * 96 * 2);
  unsigned short* mel_l = (unsigned short*)carve((size_t)T_ * B_ * 96 * 2);
  unsigned short* w1_bf = (unsigned short*)carve((size_t)512 * 512 * 2);
  unsigned short* w2_bf = (unsigned short*)carve((size_t)80 * 512 * 2);
  unsigned short* ench = (unsigned short*)carve((size_t)L_ * B_ * H_ * 2);   // t-major
  unsigned short* encl = (unsigned short*)carve((size_t)L_ * B_ * H_ * 2);
  unsigned short* h2_full = (unsigned short*)carve((size_t)T_ * B_ * H_ * 2);

  hipMemsetAsync(d_ws, 0, state_bytes, stream);

  hipFuncSetAttribute((const void*)k_enc, hipFuncAttributeMaxDynamicSharedMemorySize, ENC_LDS);
  hipFuncSetAttribute((const void*)k_dec, hipFuncAttributeMaxDynamicSharedMemorySize, DEC_LDS);
  hipFuncSetAttribute((const void*)k_mlp, hipFuncAttributeMaxDynamicSharedMemorySize, MLP_LDS);

  k_prep<<<2048, 256, 0, stream>>>(embed, tmel, mW1, mW2, emb_h, emb_l, mel_h, mel_l, w1_bf, w2_bf);
  k_sp<<<64, 512, 0, stream>>>(spk, spW1, spb1, spW2, spb2, sp);
  k_enc<<<32, 256, ENC_LDS, stream>>>(text, eWihF, eWhhF, ebF, eWihB, eWhhB, ebB,
                                      emb_h, emb_l, sp, hencfh, hencfl, ench, encl, barE);
  k_dec<<<128, 256, DEC_LDS, stream>>>(dWih0, dWhh0, db0, dWih1, dWhh1, db1,
                                       ench, encl, mel_h, mel_l,
                                       h0fh, h0fl, h1fh, h1fl, h2_full, barD);
  k_mlp<<<1000, 256, MLP_LDS, stream>>>(h2_full, w1_bf, w2_bf, mb1, mb2, stW, stb, out);
}

// Round 12
// 36101.953 us; speedup vs baseline: 1.0031x; 1.0031x over previous
//
#include <hip/hip_runtime.h>
#include <cstdint>
#include <cstddef>

// ============================================================================
// VoiceCloningGenerator — R11 (green) + ballast WGs (DVFS clock test).
// Workers byte-identical to R11. Extra blocks run a full-duty FMA grind until
// workers signal done -> sustained ~50% chip utilization keeps SCLK high.
// ============================================================================

#define DEVI __device__ __forceinline__

typedef short bf16x8 __attribute__((ext_vector_type(8)));
typedef float f32x4 __attribute__((ext_vector_type(4)));
typedef unsigned short u16x4 __attribute__((ext_vector_type(4)));

constexpr int B_ = 64, L_ = 512, T_ = 1000, E_ = 256, H_ = 512, M_ = 80, S_ = 128, Hd_ = 256;

DEVI unsigned short f2bs(float f) {
  unsigned u = __builtin_bit_cast(unsigned, f);
  unsigned r = u + 0x7fffu + ((u >> 16) & 1u);
  return (unsigned short)(r >> 16);
}
DEVI float b2f(unsigned short s) { return __builtin_bit_cast(float, (unsigned)s << 16); }
DEVI void split2(float v, unsigned short& hi, unsigned short& lo) {
  hi = f2bs(v);
  lo = f2bs(v - b2f(hi));
}
DEVI float sigm(float x) { x = fminf(fmaxf(x, -30.f), 30.f); return 1.f / (1.f + __expf(-x)); }
DEVI float tanh_(float x) { x = fminf(fmaxf(x, -15.f), 15.f); float e = __expf(2.f * x); return (e - 1.f) / (e + 1.f); }

DEVI f32x4 mfma16(bf16x8 a, bf16x8 b, f32x4 c) {
  return __builtin_amdgcn_mfma_f32_16x16x32_bf16(a, b, c, 0, 0, 0);
}

// --- asm memory ops --------------------------------------------------------
DEVI void ldg16(bf16x8& r, const unsigned short* p) {  // cached (L1/L2)
  asm volatile("global_load_dwordx4 %0, %1, off" : "=v"(r) : "v"(p));
}
DEVI void ldc16(bf16x8& r, const unsigned short* p) {  // coherence point
  asm volatile("global_load_dwordx4 %0, %1, off sc0 sc1" : "=v"(r) : "v"(p));
}
DEVI void st4c(unsigned short* p, unsigned v) {
  asm volatile("global_store_dword %0, %1, off sc0 sc1" :: "v"(p), "v"(v));
}
DEVI void sti4c(int* p, int v) {
  asm volatile("global_store_dword %0, %1, off sc0 sc1" :: "v"(p), "v"(v));
}
DEVI void st8c(unsigned short* p, u16x4 v) {
  asm volatile("global_store_dwordx2 %0, %1, off sc0 sc1" :: "v"(p), "v"(v));
}
#define WAITV(N) do { asm volatile("s_waitcnt vmcnt(" #N ")" ::: "memory"); \
                      __builtin_amdgcn_sched_barrier(0); } while (0)
#define VM_DRAIN() WAITV(0)

// --- hot-spin wait: poll load overlapped with dependent-FMA burn -----------
DEVI void hotwait(const int* p, int target) {
  int v;
  for (;;) {
    asm volatile("global_load_dword %0, %1, off sc0 sc1" : "=v"(v) : "v"(p));
    float x = 0.5f;
#pragma unroll
    for (int i = 0; i < 192; ++i)
      asm volatile("v_fmac_f32 %0, %1, %1" : "+v"(x) : "v"(x));
    asm volatile("" :: "v"(x));
    asm volatile("s_waitcnt vmcnt(0)" ::: "memory");
    __builtin_amdgcn_sched_barrier(0);
    if (v >= target) break;
  }
}

// --- ballast: 4 independent FMA chains, poll exit flag every ~4k FMAs ------
DEVI void ballast_spin(const int* dline) {
  float a = 1.f, b = 1.0000001f, c = 0.9999999f, d = 1.0000002f;
  for (;;) {
#pragma unroll 32
    for (int i = 0; i < 1024; ++i) {
      asm volatile("v_fmac_f32 %0, %1, %1" : "+v"(a) : "v"(b));
      asm volatile("v_fmac_f32 %0, %1, %1" : "+v"(b) : "v"(c));
      asm volatile("v_fmac_f32 %0, %1, %1" : "+v"(c) : "v"(d));
      asm volatile("v_fmac_f32 %0, %1, %1" : "+v"(d) : "v"(a));
    }
    asm volatile("" :: "v"(a), "v"(b), "v"(c), "v"(d));
    int v;
    asm volatile("global_load_dword %0, %1, off sc0 sc1\ns_waitcnt vmcnt(0)"
                 : "=v"(v) : "v"(dline) : "memory");
    if (v) return;
  }
}

// --- barrier: arrive tree + per-WG release flag lines; all-wave hot poll ---
struct Bar { int sub[16][16]; int master[16]; int rel[128][16]; };

template <int NWG, int NSUB>
DEVI void grid_barX(Bar* bb, int step) {
  __shared__ int finS;
  const int tid = threadIdx.x;
  __syncthreads();
  if (tid == 0) {
    finS = 0;
    constexpr int per = NWG / NSUB;
    int old = __hip_atomic_fetch_add(&bb->sub[(int)blockIdx.x % NSUB][0], 1,
                                     __ATOMIC_RELAXED, __HIP_MEMORY_SCOPE_AGENT);
    if (old == per * (step + 1) - 1) {
      int om = __hip_atomic_fetch_add(&bb->master[0], 1,
                                      __ATOMIC_RELAXED, __HIP_MEMORY_SCOPE_AGENT);
      if (om == NSUB * (step + 1) - 1) finS = 1;
    }
  }
  __syncthreads();
  if (finS && tid < NWG) sti4c(&bb->rel[tid][0], step + 1);   // 1 line per WG
  hotwait(&bb->rel[(int)blockIdx.x][0], step + 1);            // all waves, hot
}

// --- 3-deep pipelined load/MFMA loop; batch = 8 asm loads ------------------
template <int N, class FI, class FM>
DEVI void pipe3(FI issue, FM domf) {
  bf16x8 S0[8], S1[8], S2[8];
  issue(0, S0);
  if constexpr (N > 1) issue(1, S1);
  if constexpr (N > 2) issue(2, S2);
#pragma unroll
  for (int j = 0; j < N; ++j) {
    if (j + 2 < N) { WAITV(16); } else if (j + 1 < N) { WAITV(8); } else { WAITV(0); }
    if (j % 3 == 0)      { domf(j, S0); if (j + 3 < N) issue(j + 3, S0); }
    else if (j % 3 == 1) { domf(j, S1); if (j + 3 < N) issue(j + 3, S1); }
    else                 { domf(j, S2); if (j + 3 < N) issue(j + 3, S2); }
  }
}

// ---------------------------------------------------------------------------
__global__ void k_prep(const float* __restrict__ embed, const float* __restrict__ tmel,
                       const float* __restrict__ mw1, const float* __restrict__ mw2,
                       unsigned short* emb_h, unsigned short* emb_l,
                       unsigned short* mel_h, unsigned short* mel_l,
                       unsigned short* w1_bf, unsigned short* w2_bf) {
  const long long stride = (long long)gridDim.x * blockDim.x;
  const long long i0 = (long long)blockIdx.x * blockDim.x + threadIdx.x;
  for (long long i = i0; i < 256 * 256; i += stride) {
    unsigned short h, l; split2(embed[i], h, l);
    emb_h[i] = h; emb_l[i] = l;
  }
  for (long long i = i0; i < (long long)T_ * B_ * 96; i += stride) {
    int c = (int)(i % 96);
    long long tb = i / 96;
    int b = (int)(tb % B_);
    int t = (int)(tb / B_);
    float v = 0.f;
    if (t > 0 && c < 80) v = tmel[((long long)b * T_ + (t - 1)) * M_ + c];
    unsigned short h, l; split2(v, h, l);
    mel_h[i] = h; mel_l[i] = l;
  }
  for (long long i = i0; i < 512 * 512; i += stride) w1_bf[i] = f2bs(mw1[i]);
  for (long long i = i0; i < 80 * 512; i += stride) w2_bf[i] = f2bs(mw2[i]);
}

// ---------------------------------------------------------------------------
__global__ void __launch_bounds__(512) k_sp(const float* __restrict__ spk,
                                            const float* __restrict__ w1, const float* __restrict__ b1,
                                            const float* __restrict__ w2, const float* __restrict__ b2,
                                            float* sp) {
  __shared__ float t1[512];
  const int b = blockIdx.x, j = threadIdx.x;
  float a = b1[j];
  const float* sr = spk + b * S_;
  for (int k = 0; k < S_; ++k) a += sr[k] * w1[j * S_ + k];
  t1[j] = fmaxf(a, 0.f);
  __syncthreads();
  float a2 = b2[j];
  for (int k = 0; k < H_; ++k) a2 += t1[k] * w2[j * H_ + k];
  sp[b * H_ + j] = a2;
}

// ---------------------------------------------------------------------------
// Encoder: workers = blocks 0..31 (2 dirs x 16 cg); blocks 32..255 = ballast.
// ---------------------------------------------------------------------------
constexpr int ENC_LDS = 2 * 16 * 4 * 64 * 16 + 4 * 64 * 16 * 4 + 256;  // 147712

__global__ void __launch_bounds__(256, 1) k_enc(
    const int* __restrict__ text,
    const float* __restrict__ WihF, const float* __restrict__ WhhF, const float* __restrict__ bF,
    const float* __restrict__ WihB, const float* __restrict__ WhhB, const float* __restrict__ bB,
    const unsigned short* __restrict__ emb_h, const unsigned short* __restrict__ emb_l,
    const float* __restrict__ sp,
    unsigned short* hencfh, unsigned short* hencfl,
    unsigned short* ench, unsigned short* encl, Bar* bar, int* doneE) {
  if ((int)blockIdx.x >= 32) { ballast_spin(&doneE[(int)blockIdx.x * 16]); return; }
  extern __shared__ char lds[];
  unsigned short* Wh = (unsigned short*)lds;
  unsigned short* Wl = Wh + 16 * 4 * 64 * 8;
  float* G = (float*)(lds + 2 * 16 * 4 * 64 * 16);
  float* bias = G + 4 * 64 * 16;

  const int wg = blockIdx.x;
  const int dir = wg >> 4;
  const int jhb = (wg & 15) * 16;
  const int tid = threadIdx.x;
  const int wv = tid >> 6, ln = tid & 63, lg = ln >> 4, lr = ln & 15;

  const float* Wih = dir ? WihB : WihF;
  const float* Whh = dir ? WhhB : WhhF;
  const float* bb = dir ? bB : bF;

  for (int s = tid; s < 16 * 4 * 64; s += 256) {
    int kb = s >> 8, g = (s >> 6) & 3, l = s & 63;
    int R = g * Hd_ + jhb + (l & 15);
    int k0 = kb * 32 + (l >> 4) * 8;
    const float* src = (k0 < E_) ? (Wih + (size_t)R * E_ + k0) : (Whh + (size_t)R * Hd_ + (k0 - E_));
    bf16x8 vh, vl;
#pragma unroll
    for (int j = 0; j < 8; ++j) {
      unsigned short a, b; split2(src[j], a, b);
      vh[j] = (short)a; vl[j] = (short)b;
    }
    *(bf16x8*)(Wh + (size_t)s * 8) = vh;
    *(bf16x8*)(Wl + (size_t)s * 8) = vl;
  }
  if (tid < 64) bias[tid] = bb[(tid >> 4) * Hd_ + jhb + (tid & 15)];

  const int eb = tid >> 2, ej0 = (tid & 3) * 4;
  float c4[4] = {0.f, 0.f, 0.f, 0.f};
  float spv[4];
#pragma unroll
  for (int q = 0; q < 4; ++q) spv[q] = sp[eb * H_ + dir * Hd_ + jhb + ej0 + q];

  const int jh = jhb + ej0;
  const size_t fro = ((size_t)((jh >> 5) * 4 + (eb >> 4)) * 64 +
                      (((jh >> 3) & 3) * 16 + (eb & 15))) * 8 + (jh & 7);

  __syncthreads();

  for (int t = 0; t < L_; ++t) {
    const int tpos = dir ? (L_ - 1 - t) : t;
    const unsigned short* hsh = hencfh + ((size_t)((t & 1) * 2 + dir)) * 16384;
    const unsigned short* hsl = hencfl + ((size_t)((t & 1) * 2 + dir)) * 16384;
    unsigned short* hdh = hencfh + ((size_t)(((t + 1) & 1) * 2 + dir)) * 16384;
    unsigned short* hdl = hencfl + ((size_t)(((t + 1) & 1) * 2 + dir)) * 16384;

    for (int i = tid; i < 4096; i += 256) G[i] = bias[((i >> 10) << 4) + (i & 15)];

    int tix[4];
#pragma unroll
    for (int m = 0; m < 4; ++m) tix[m] = text[(16 * m + lr) * L_ + tpos];

    f32x4 acc[4][4];
#pragma unroll
    for (int g = 0; g < 4; ++g)
#pragma unroll
      for (int m = 0; m < 4; ++m) acc[g][m] = (f32x4){0.f, 0.f, 0.f, 0.f};

    auto issue = [&](int j, bf16x8 (&S)[8]) {
      const int kb = wv + 4 * j;
      if (kb < 8) {
        const int k0 = kb * 32 + lg * 8;
#pragma unroll
        for (int m = 0; m < 4; ++m) {
          ldg16(S[m],     emb_h + (size_t)tix[m] * E_ + k0);
          ldg16(S[4 + m], emb_l + (size_t)tix[m] * E_ + k0);
        }
      } else {
        const unsigned short* ph = hsh + ((size_t)((kb - 8) * 4) * 64 + ln) * 8;
        const unsigned short* pl = hsl + ((size_t)((kb - 8) * 4) * 64 + ln) * 8;
#pragma unroll
        for (int m = 0; m < 4; ++m) { ldc16(S[m], ph + m * 512); ldc16(S[4 + m], pl + m * 512); }
      }
    };
    auto domf = [&](int j, bf16x8 (&S)[8]) {
      const int kb = wv + 4 * j;
#pragma unroll
      for (int g = 0; g < 4; ++g) {
        bf16x8 bh = *(bf16x8*)(Wh + ((size_t)(kb * 4 + g) * 64 + ln) * 8);
        bf16x8 bl = *(bf16x8*)(Wl + ((size_t)(kb * 4 + g) * 64 + ln) * 8);
#pragma unroll
        for (int m = 0; m < 4; ++m) {
          acc[g][m] = mfma16(S[m],     bh, acc[g][m]);
          acc[g][m] = mfma16(S[4 + m], bh, acc[g][m]);
          acc[g][m] = mfma16(S[m],     bl, acc[g][m]);
        }
      }
    };
    pipe3<4>(issue, domf);

    __syncthreads();
#pragma unroll
    for (int g = 0; g < 4; ++g)
#pragma unroll
      for (int m = 0; m < 4; ++m)
#pragma unroll
        for (int r = 0; r < 4; ++r)
          atomicAdd(&G[(g * 64 + 16 * m + 4 * lg + r) * 16 + lr], acc[g][m][r]);
    __syncthreads();

    {
      u16x4 hvh, hvl, ovh, ovl;
#pragma unroll
      for (int q = 0; q < 4; ++q) {
        int jj = ej0 + q;
        float gi = G[(0 * 64 + eb) * 16 + jj];
        float gf = G[(1 * 64 + eb) * 16 + jj];
        float gg = G[(2 * 64 + eb) * 16 + jj];
        float go = G[(3 * 64 + eb) * 16 + jj];
        float cn = sigm(gf) * c4[q] + sigm(gi) * tanh_(gg);
        c4[q] = cn;
        float h = sigm(go) * tanh_(cn);
        unsigned short a, b; split2(h, a, b);
        hvh[q] = a; hvl[q] = b;
        float o = h + spv[q];
        split2(o, a, b);
        ovh[q] = a; ovl[q] = b;
      }
      st8c(hdh + fro, hvh);
      st8c(hdl + fro, hvl);
      // t-major enc_out: [t][B][H]
      *(u16x4*)(ench + ((size_t)tpos * B_ + eb) * H_ + dir * Hd_ + jhb + ej0) = ovh;
      *(u16x4*)(encl + ((size_t)tpos * B_ + eb) * H_ + dir * Hd_ + jhb + ej0) = ovl;
    }
    VM_DRAIN();
    grid_barX<32, 8>(bar, t);
  }
  // release ballast (each worker signals 7 ballast blocks: 32..255)
  if (tid < 7) sti4c(&doneE[(32 + wg * 7 + tid) * 16], 1);
}

// ---------------------------------------------------------------------------
// Decoder: workers = blocks 0..127; blocks 128..255 = ballast.
// ---------------------------------------------------------------------------
constexpr int DEC_LDS = 2 * 35 * 2 * 64 * 16 + 4 * 64 * 8 * 4 + 128;  // 151680

__global__ void __launch_bounds__(256, 1) k_dec(
    const float* __restrict__ Wih0, const float* __restrict__ Whh0, const float* __restrict__ b0,
    const float* __restrict__ Wih1, const float* __restrict__ Whh1, const float* __restrict__ b1,
    const unsigned short* __restrict__ ench, const unsigned short* __restrict__ encl,
    const unsigned short* __restrict__ melh, const unsigned short* __restrict__ mell,
    unsigned short* h0fh, unsigned short* h0fl,
    unsigned short* h1fh, unsigned short* h1fl,
    unsigned short* h2_full, Bar* bar, int* doneD) {
  if ((int)blockIdx.x >= 128) { ballast_spin(&doneD[(int)blockIdx.x * 16]); return; }
  extern __shared__ char lds[];
  const int wg = blockIdx.x;
  const int layer = wg >> 6;
  const int jcb = (wg & 63) * 8;
  const int tid = threadIdx.x, wv = tid >> 6, ln = tid & 63, lg = ln >> 4, lr = ln & 15;
  const int NKB = layer ? 32 : 35;
  unsigned short* Wh = (unsigned short*)lds;
  unsigned short* Wl = Wh + (size_t)NKB * 2 * 64 * 8;
  float* G = (float*)(lds + (size_t)2 * NKB * 2 * 64 * 16);
  float* bias = G + 4 * 64 * 8;

  if (layer == 0) {
    for (int s = tid; s < 35 * 2 * 64; s += 256) {
      int kb = s >> 7, st = (s >> 6) & 1, l = s & 63;
      int n = l & 15;
      int R = (2 * st + (n >> 3)) * H_ + jcb + (n & 7);
      int k0 = kb * 32 + (l >> 4) * 8;
      bf16x8 vh, vl;
      if (k0 < 96) {
#pragma unroll
        for (int j = 0; j < 8; ++j) {
          int c = k0 + j;
          float v = (c < 80) ? Wih0[(size_t)R * 592 + c] : 0.f;
          unsigned short a, b; split2(v, a, b);
          vh[j] = (short)a; vl[j] = (short)b;
        }
      } else if (k0 < 608) {
        const float* src = Wih0 + (size_t)R * 592 + (k0 - 16);
#pragma unroll
        for (int j = 0; j < 8; ++j) {
          unsigned short a, b; split2(src[j], a, b);
          vh[j] = (short)a; vl[j] = (short)b;
        }
      } else {
        const float* src = Whh0 + (size_t)R * H_ + (k0 - 608);
#pragma unroll
        for (int j = 0; j < 8; ++j) {
          unsigned short a, b; split2(src[j], a, b);
          vh[j] = (short)a; vl[j] = (short)b;
        }
      }
      *(bf16x8*)(Wh + (size_t)s * 8) = vh;
      *(bf16x8*)(Wl + (size_t)s * 8) = vl;
    }
    if (tid < 32) bias[tid] = b0[(tid >> 3) * H_ + jcb + (tid & 7)];
  } else {
    for (int s = tid; s < 32 * 2 * 64; s += 256) {
      int kb = s >> 7, st = (s >> 6) & 1, l = s & 63;
      int n = l & 15;
      int R = (2 * st + (n >> 3)) * H_ + jcb + (n & 7);
      int k0 = kb * 32 + (l >> 4) * 8;
      const float* src = (k0 < 512) ? (Wih1 + (size_t)R * H_ + k0) : (Whh1 + (size_t)R * H_ + (k0 - 512));
      bf16x8 vh, vl;
#pragma unroll
      for (int j = 0; j < 8; ++j) {
        unsigned short a, b; split2(src[j], a, b);
        vh[j] = (short)a; vl[j] = (short)b;
      }
      *(bf16x8*)(Wh + (size_t)s * 8) = vh;
      *(bf16x8*)(Wl + (size_t)s * 8) = vl;
    }
    if (tid < 32) bias[tid] = b1[(tid >> 3) * H_ + jcb + (tid & 7)];
  }

  const int ebd = tid & 63, cc0 = (tid >> 6) * 2;
  float c2[2] = {0.f, 0.f};
  const int j0w = jcb + cc0;
  const size_t frw = ((size_t)((j0w >> 5) * 4 + (ebd >> 4)) * 64 +
                      (((j0w >> 3) & 3) * 16 + (ebd & 15))) * 8 + (j0w & 7);
  __syncthreads();

  for (int tau = 0; tau <= T_; ++tau) {
    const bool active = (layer == 0) ? (tau < T_) : (tau >= 1);
    if (active) {
      const int t = (layer == 0) ? tau : tau - 1;
      for (int i = tid; i < 2048; i += 256) G[i] = bias[((i >> 9) << 3) + (i & 7)];

      f32x4 acc[2][4];
#pragma unroll
      for (int st = 0; st < 2; ++st)
#pragma unroll
        for (int m = 0; m < 4; ++m) acc[st][m] = (f32x4){0.f, 0.f, 0.f, 0.f};

      auto MF = [&](int kb, bf16x8 (&S)[8]) {
#pragma unroll
        for (int st = 0; st < 2; ++st) {
          bf16x8 bh = *(bf16x8*)(Wh + ((size_t)(kb * 2 + st) * 64 + ln) * 8);
          bf16x8 bl = *(bf16x8*)(Wl + ((size_t)(kb * 2 + st) * 64 + ln) * 8);
#pragma unroll
          for (int m = 0; m < 4; ++m) {
            acc[st][m] = mfma16(S[m],     bh, acc[st][m]);
            acc[st][m] = mfma16(S[4 + m], bh, acc[st][m]);
            acc[st][m] = mfma16(S[m],     bl, acc[st][m]);
          }
        }
      };

      if (layer == 0) {
        const int tq = t & (L_ - 1);
        const unsigned short* p0h = h0fh + (size_t)((tau + 1) & 1) * 32768;
        const unsigned short* p0l = h0fl + (size_t)((tau + 1) & 1) * 32768;
        auto issue = [&](int j, bf16x8 (&S)[8]) {
          const int kb = wv + 4 * j;
          const int k0 = kb * 32 + lg * 8;
          if (kb < 3) {
#pragma unroll
            for (int m = 0; m < 4; ++m) {
              ldg16(S[m],     melh + ((size_t)t * B_ + 16 * m + lr) * 96 + k0);
              ldg16(S[4 + m], mell + ((size_t)t * B_ + 16 * m + lr) * 96 + k0);
            }
          } else if (kb < 19) {
            const int k = k0 - 96;
#pragma unroll
            for (int m = 0; m < 4; ++m) {
              ldg16(S[m],     ench + ((size_t)tq * B_ + 16 * m + lr) * H_ + k);  // t-major
              ldg16(S[4 + m], encl + ((size_t)tq * B_ + 16 * m + lr) * H_ + k);
            }
          } else {
            const unsigned short* ph = p0h + ((size_t)((kb - 19) * 4) * 64 + ln) * 8;
            const unsigned short* pl = p0l + ((size_t)((kb - 19) * 4) * 64 + ln) * 8;
#pragma unroll
            for (int m = 0; m < 4; ++m) { ldc16(S[m], ph + m * 512); ldc16(S[4 + m], pl + m * 512); }
          }
        };
        auto domf = [&](int j, bf16x8 (&S)[8]) { MF(wv + 4 * j, S); };
        if (wv < 3) pipe3<9>(issue, domf);
        else        pipe3<8>(issue, domf);
      } else {
        const unsigned short* q0h = h0fh + (size_t)((tau + 1) & 1) * 32768;
        const unsigned short* q0l = h0fl + (size_t)((tau + 1) & 1) * 32768;
        const unsigned short* q1h = h1fh + (size_t)(tau & 1) * 32768;
        const unsigned short* q1l = h1fl + (size_t)(tau & 1) * 32768;
        auto issue = [&](int j, bf16x8 (&S)[8]) {
          const int kb = wv + 4 * j;
          const unsigned short* ph = (kb < 16) ? (q0h + ((size_t)(kb * 4) * 64 + ln) * 8)
                                               : (q1h + ((size_t)((kb - 16) * 4) * 64 + ln) * 8);
          const unsigned short* pl = (kb < 16) ? (q0l + ((size_t)(kb * 4) * 64 + ln) * 8)
                                               : (q1l + ((size_t)((kb - 16) * 4) * 64 + ln) * 8);
#pragma unroll
          for (int m = 0; m < 4; ++m) { ldc16(S[m], ph + m * 512); ldc16(S[4 + m], pl + m * 512); }
        };
        auto domf = [&](int j, bf16x8 (&S)[8]) { MF(wv + 4 * j, S); };
        pipe3<8>(issue, domf);
      }

      __syncthreads();
#pragma unroll
      for (int st = 0; st < 2; ++st)
#pragma unroll
        for (int m = 0; m < 4; ++m)
#pragma unroll
          for (int r = 0; r < 4; ++r) {
            int g = 2 * st + (lr >> 3), col = lr & 7;
            atomicAdd(&G[(g * 64 + 16 * m + 4 * lg + r) * 8 + col], acc[st][m][r]);
          }
      __syncthreads();

      {
        unsigned short* dh = layer ? (h1fh + (size_t)((tau + 1) & 1) * 32768)
                                   : (h0fh + (size_t)(tau & 1) * 32768);
        unsigned short* dl = layer ? (h1fl + (size_t)((tau + 1) & 1) * 32768)
                                   : (h0fl + (size_t)(tau & 1) * 32768);
        unsigned short hh[2], hl[2];
#pragma unroll
        for (int q = 0; q < 2; ++q) {
          int c = cc0 + q;
          float gi = G[(0 * 64 + ebd) * 8 + c];
          float gf = G[(1 * 64 + ebd) * 8 + c];
          float gg = G[(2 * 64 + ebd) * 8 + c];
          float go = G[(3 * 64 + ebd) * 8 + c];
          float cn = sigm(gf) * c2[q] + sigm(gi) * tanh_(gg);
          c2[q] = cn;
          float h = sigm(go) * tanh_(cn);
          split2(h, hh[q], hl[q]);
        }
        unsigned ph = (unsigned)hh[0] | ((unsigned)hh[1] << 16);
        unsigned pl = (unsigned)hl[0] | ((unsigned)hl[1] << 16);
        st4c(dh + frw, ph);
        st4c(dl + frw, pl);
        if (layer) *(unsigned*)(h2_full + ((size_t)t * B_ + ebd) * H_ + jcb + cc0) = ph;
      }
      VM_DRAIN();
    }
    grid_barX<128, 16>(bar, tau);
  }
  // release ballast (worker wg signals ballast block 128+wg)
  if (tid == 0) sti4c(&doneD[(128 + wg) * 16], 1);
}

// ---------------------------------------------------------------------------
constexpr int MLP_LDS = 64 * 1024;

__global__ void __launch_bounds__(256) k_mlp(
    const unsigned short* __restrict__ h2_full,
    const unsigned short* __restrict__ w1_bf, const unsigned short* __restrict__ w2_bf,
    const float* __restrict__ mb1, const float* __restrict__ mb2,
    const float* __restrict__ stW, const float* __restrict__ stb, float* out) {
  extern __shared__ char lds[];
  const int t = blockIdx.x;
  const int tid = threadIdx.x, wv = tid >> 6, ln = tid & 63, lg = ln >> 4, lr = ln & 15;
  const unsigned short* A = h2_full + (size_t)t * B_ * H_;

  for (int half = 0; half < 2; ++half) {
    const int nb = wv * 8 + half * 4;
    f32x4 acc[4][4];
#pragma unroll
    for (int nn = 0; nn < 4; ++nn) {
      float bv = mb1[(nb + nn) * 16 + lr];
#pragma unroll
      for (int m = 0; m < 4; ++m) acc[m][nn] = (f32x4){bv, bv, bv, bv};
    }
    for (int kb = 0; kb < 16; ++kb) {
      int k0 = kb * 32 + lg * 8;
      bf16x8 afr[4], bfr[4];
#pragma unroll
      for (int m = 0; m < 4; ++m) afr[m] = *(const bf16x8*)(A + (size_t)(16 * m + lr) * H_ + k0);
#pragma unroll
      for (int nn = 0; nn < 4; ++nn) bfr[nn] = *(const bf16x8*)(w1_bf + (size_t)((nb + nn) * 16 + lr) * H_ + k0);
#pragma unroll
      for (int m = 0; m < 4; ++m)
#pragma unroll
        for (int nn = 0; nn < 4; ++nn) acc[m][nn] = mfma16(afr[m], bfr[nn], acc[m][nn]);
    }
#pragma unroll
    for (int m = 0; m < 4; ++m)
#pragma unroll
      for (int nn = 0; nn < 4; ++nn)
#pragma unroll
        for (int r = 0; r < 4; ++r) {
          int row = 16 * m + 4 * lg + r, col = (nb + nn) * 16 + lr;
          *(unsigned short*)(lds + row * 1024 + ((col * 2) ^ ((row & 7) << 4))) =
              f2bs(fmaxf(acc[m][nn][r], 0.f));
        }
  }
  __syncthreads();

  {
    f32x4 acc2[5];
#pragma unroll
    for (int n = 0; n < 5; ++n) {
      float bv = mb2[n * 16 + lr];
      acc2[n] = (f32x4){bv, bv, bv, bv};
    }
    for (int kb = 0; kb < 16; ++kb) {
      int k0 = kb * 32 + lg * 8;
      int row = 16 * wv + lr;
      bf16x8 afr = *(bf16x8*)(lds + row * 1024 + ((k0 * 2) ^ ((row & 7) << 4)));
#pragma unroll
      for (int n = 0; n < 5; ++n) {
        bf16x8 bfr = *(const bf16x8*)(w2_bf + (size_t)(n * 16 + lr) * H_ + k0);
        acc2[n] = mfma16(afr, bfr, acc2[n]);
      }
    }
#pragma unroll
    for (int n = 0; n < 5; ++n)
#pragma unroll
      for (int r = 0; r < 4; ++r) {
        int b = 16 * wv + 4 * lg + r;
        out[((size_t)b * T_ + t) * M_ + n * 16 + lr] = acc2[n][r];
      }
  }

  if (tid < 64) {
    int b = tid;
    float s = stb[0];
    const unsigned short* hp = A + (size_t)b * H_;
    for (int k = 0; k < H_; ++k) s += b2f(hp[k]) * stW[k];
    out[(size_t)B_ * T_ * M_ + (size_t)b * T_ + t] = s;
  }
}

// ---------------------------------------------------------------------------
extern "C" void kernel_launch(void* const* d_in, const int* in_sizes, int n_in,
                              void* d_out, int out_size, void* d_ws, size_t ws_size,
                              hipStream_t stream) {
  (void)in_sizes; (void)n_in; (void)out_size; (void)ws_size;
  const int* text = (const int*)d_in[0];
  const float* spk = (const float*)d_in[1];
  const float* tmel = (const float*)d_in[2];
  const float* embed = (const float*)d_in[3];
  const float* eWihF = (const float*)d_in[4];
  const float* eWhhF = (const float*)d_in[5];
  const float* ebF = (const float*)d_in[6];
  const float* eWihB = (const float*)d_in[7];
  const float* eWhhB = (const float*)d_in[8];
  const float* ebB = (const float*)d_in[9];
  const float* spW1 = (const float*)d_in[10];
  const float* spb1 = (const float*)d_in[11];
  const float* spW2 = (const float*)d_in[12];
  const float* spb2 = (const float*)d_in[13];
  const float* dWih0 = (const float*)d_in[14];
  const float* dWhh0 = (const float*)d_in[15];
  const float* db0 = (const float*)d_in[16];
  const float* dWih1 = (const float*)d_in[17];
  const float* dWhh1 = (const float*)d_in[18];
  const float* db1 = (const float*)d_in[19];
  const float* mW1 = (const float*)d_in[20];
  const float* mb1 = (const float*)d_in[21];
  const float* mW2 = (const float*)d_in[22];
  const float* mb2 = (const float*)d_in[23];
  const float* stW = (const float*)d_in[24];
  const float* stb = (const float*)d_in[25];
  float* out = (float*)d_out;

  char* base = (char*)d_ws;
  size_t off = 0;
  auto carve = [&](size_t bytes) -> void* {
    void* p = base + off;
    off += (bytes + 255) & ~(size_t)255;
    return p;
  };
  // --- state region (zeroed each call) ---
  Bar* barE = (Bar*)carve(sizeof(Bar));
  Bar* barD = (Bar*)carve(sizeof(Bar));
  int* doneE = (int*)carve(256 * 16 * 4);
  int* doneD = (int*)carve(256 * 16 * 4);
  unsigned short* h0fh = (unsigned short*)carve((size_t)2 * 32768 * 2);
  unsigned short* h0fl = (unsigned short*)carve((size_t)2 * 32768 * 2);
  unsigned short* h1fh = (unsigned short*)carve((size_t)2 * 32768 * 2);
  unsigned short* h1fl = (unsigned short*)carve((size_t)2 * 32768 * 2);
  unsigned short* hencfh = (unsigned short*)carve((size_t)4 * 16384 * 2);
  unsigned short* hencfl = (unsigned short*)carve((size_t)4 * 16384 * 2);
  const size_t state_bytes = off;
  // --- write-before-read buffers ---
  float* sp = (float*)carve((size_t)B_ * H_ * 4);
  unsigned short* emb_h = (unsigned short*)carve((size_t)256 * 256 * 2);
  unsigned short* emb_l = (unsigned short*)carve((size_t)256 * 256 * 2);
  unsigned short* mel_h = (unsigned short*)carve((size_t)T_ * B_ * 96 * 2);
  unsigned short* mel_l = (unsigned short*)carve((size_t)T_ * B_ * 96 * 2);
  unsigned short* w1_bf = (unsigned short*)carve((size_t)512 * 512 * 2);
  unsigned short* w2_bf = (unsigned short*)carve((size_t)80 * 512 * 2);
  unsigned short* ench = (unsigned short*)carve((size_t)L_ * B_ * H_ * 2);   // t-major
  unsigned short* encl = (unsigned short*)carve((size_t)L_ * B_ * H_ * 2);
  unsigned short* h2_full = (unsigned short*)carve((size_t)T_ * B_ * H_ * 2);

  hipMemsetAsync(d_ws, 0, state_bytes, stream);

  hipFuncSetAttribute((const void*)k_enc, hipFuncAttributeMaxDynamicSharedMemorySize, ENC_LDS);
  hipFuncSetAttribute((const void*)k_dec, hipFuncAttributeMaxDynamicSharedMemorySize, DEC_LDS);
  hipFuncSetAttribute((const void*)k_mlp, hipFuncAttributeMaxDynamicSharedMemorySize, MLP_LDS);

  k_prep<<<2048, 256, 0, stream>>>(embed, tmel, mW1, mW2, emb_h, emb_l, mel_h, mel_l, w1_bf, w2_bf);
  k_sp<<<64, 512, 0, stream>>>(spk, spW1, spb1, spW2, spb2, sp);
  k_enc<<<256, 256, ENC_LDS, stream>>>(text, eWihF, eWhhF, ebF, eWihB, eWhhB, ebB,
                                       emb_h, emb_l, sp, hencfh, hencfl, ench, encl, barE, doneE);
  k_dec<<<256, 256, DEC_LDS, stream>>>(dWih0, dWhh0, db0, dWih1, dWhh1, db1,
                                       ench, encl, mel_h, mel_l,
                                       h0fh, h0fl, h1fh, h1fl, h2_full, barD, doneD);
  k_mlp<<<1000, 256, MLP_LDS, stream>>>(h2_full, w1_bf, w2_bf, mb1, mb2, stW, stb, out);
}

// Round 13
// 33753.387 us; speedup vs baseline: 1.0729x; 1.0696x over previous
//
#include <hip/hip_runtime.h>
#include <cstdint>
#include <cstddef>

// ============================================================================
// VoiceCloningGenerator — tagged-dataflow round.
// Barrier removed from the critical path: producers tag their h-fragments
// (tag = step+1) after draining stores; consumers poll the 64 producer tags
// with one 64-lane load + __all, then load h. WAR protection via 4-slot h
// rings + a monotonic arrive counter waited on 3 ticks late (latency hidden).
// ============================================================================

#define DEVI __device__ __forceinline__

typedef short bf16x8 __attribute__((ext_vector_type(8)));
typedef float f32x4 __attribute__((ext_vector_type(4)));
typedef unsigned short u16x4 __attribute__((ext_vector_type(4)));

constexpr int B_ = 64, L_ = 512, T_ = 1000, E_ = 256, H_ = 512, M_ = 80, S_ = 128, Hd_ = 256;

DEVI unsigned short f2bs(float f) {
  unsigned u = __builtin_bit_cast(unsigned, f);
  unsigned r = u + 0x7fffu + ((u >> 16) & 1u);
  return (unsigned short)(r >> 16);
}
DEVI float b2f(unsigned short s) { return __builtin_bit_cast(float, (unsigned)s << 16); }
DEVI void split2(float v, unsigned short& hi, unsigned short& lo) {
  hi = f2bs(v);
  lo = f2bs(v - b2f(hi));
}
DEVI float sigm(float x) { x = fminf(fmaxf(x, -30.f), 30.f); return 1.f / (1.f + __expf(-x)); }
DEVI float tanh_(float x) { x = fminf(fmaxf(x, -15.f), 15.f); float e = __expf(2.f * x); return (e - 1.f) / (e + 1.f); }

DEVI f32x4 mfma16(bf16x8 a, bf16x8 b, f32x4 c) {
  return __builtin_amdgcn_mfma_f32_16x16x32_bf16(a, b, c, 0, 0, 0);
}

// --- asm memory ops ---------------------------------------------------------
DEVI void ldg16(bf16x8& r, const unsigned short* p) {  // cached (L1/L2)
  asm volatile("global_load_dwordx4 %0, %1, off" : "=v"(r) : "v"(p));
}
DEVI void ldc16(bf16x8& r, const unsigned short* p) {  // coherence point
  asm volatile("global_load_dwordx4 %0, %1, off sc0 sc1" : "=v"(r) : "v"(p));
}
DEVI void st4c(unsigned short* p, unsigned v) {
  asm volatile("global_store_dword %0, %1, off sc0 sc1" :: "v"(p), "v"(v));
}
DEVI void sti4c(int* p, int v) {
  asm volatile("global_store_dword %0, %1, off sc0 sc1" :: "v"(p), "v"(v));
}
DEVI void st8c(unsigned short* p, u16x4 v) {
  asm volatile("global_store_dwordx2 %0, %1, off sc0 sc1" :: "v"(p), "v"(v));
}
#define WAITV(N) do { asm volatile("s_waitcnt vmcnt(" #N ")" ::: "memory"); \
                      __builtin_amdgcn_sched_barrier(0); } while (0)
#define VM_DRAIN() WAITV(0)

DEVI void burn64() {
  float x = 0.5f;
#pragma unroll
  for (int i = 0; i < 64; ++i)
    asm volatile("v_fmac_f32 %0, %1, %1" : "+v"(x) : "v"(x));
  asm volatile("" :: "v"(x));
}

// --- tag / WAR waits ---------------------------------------------------------
DEVI void tagwait1(const int* tags, int idx, int thr) {
  const int* p = tags + idx;
  for (;;) {
    int v;
    asm volatile("global_load_dword %0, %1, off sc0 sc1" : "=v"(v) : "v"(p));
    burn64();
    asm volatile("s_waitcnt vmcnt(0)" ::: "memory");
    __builtin_amdgcn_sched_barrier(0);
    if (__all(v >= thr)) break;
  }
}
DEVI void tagwait2(const int* t0, const int* t1, int idx, int a, int b) {
  const int* p0 = t0 + idx;
  const int* p1 = t1 + idx;
  for (;;) {
    int v0, v1;
    asm volatile("global_load_dword %0, %1, off sc0 sc1" : "=v"(v0) : "v"(p0));
    asm volatile("global_load_dword %0, %1, off sc0 sc1" : "=v"(v1) : "v"(p1));
    burn64();
    asm volatile("s_waitcnt vmcnt(0)" ::: "memory");
    __builtin_amdgcn_sched_barrier(0);
    if (__all(v0 >= a) && __all(v1 >= b)) break;
  }
}
DEVI void warwait(const int* cnt, int thr) {
  for (;;) {
    int v;
    asm volatile("global_load_dword %0, %1, off sc0 sc1" : "=v"(v) : "v"(cnt));
    burn64();
    asm volatile("s_waitcnt vmcnt(0)" ::: "memory");
    __builtin_amdgcn_sched_barrier(0);
    if (v >= thr) break;
  }
}

// ---------------------------------------------------------------------------
__global__ void k_prep(const float* __restrict__ embed, const float* __restrict__ tmel,
                       const float* __restrict__ mw1, const float* __restrict__ mw2,
                       unsigned short* emb_h, unsigned short* emb_l,
                       unsigned short* mel_h, unsigned short* mel_l,
                       unsigned short* w1_bf, unsigned short* w2_bf) {
  const long long stride = (long long)gridDim.x * blockDim.x;
  const long long i0 = (long long)blockIdx.x * blockDim.x + threadIdx.x;
  for (long long i = i0; i < 256 * 256; i += stride) {
    unsigned short h, l; split2(embed[i], h, l);
    emb_h[i] = h; emb_l[i] = l;
  }
  for (long long i = i0; i < (long long)T_ * B_ * 96; i += stride) {
    int c = (int)(i % 96);
    long long tb = i / 96;
    int b = (int)(tb % B_);
    int t = (int)(tb / B_);
    float v = 0.f;
    if (t > 0 && c < 80) v = tmel[((long long)b * T_ + (t - 1)) * M_ + c];
    unsigned short h, l; split2(v, h, l);
    mel_h[i] = h; mel_l[i] = l;
  }
  for (long long i = i0; i < 512 * 512; i += stride) w1_bf[i] = f2bs(mw1[i]);
  for (long long i = i0; i < 80 * 512; i += stride) w2_bf[i] = f2bs(mw2[i]);
}

// ---------------------------------------------------------------------------
__global__ void __launch_bounds__(512) k_sp(const float* __restrict__ spk,
                                            const float* __restrict__ w1, const float* __restrict__ b1,
                                            const float* __restrict__ w2, const float* __restrict__ b2,
                                            float* sp) {
  __shared__ float t1[512];
  const int b = blockIdx.x, j = threadIdx.x;
  float a = b1[j];
  const float* sr = spk + b * S_;
  for (int k = 0; k < S_; ++k) a += sr[k] * w1[j * S_ + k];
  t1[j] = fmaxf(a, 0.f);
  __syncthreads();
  float a2 = b2[j];
  for (int k = 0; k < H_; ++k) a2 += t1[k] * w2[j * H_ + k];
  sp[b * H_ + j] = a2;
}

// ---------------------------------------------------------------------------
// Encoder: 2 INDEPENDENT dirs x 16 WGs x 16 cols. h ring: 4 slots per dir,
// frag [slot*2+dir][8kb][4m][64][8]. Tags tagHE[dir*16+cg] = t+1. WAR via
// warE[dir*16] counter, waited 3 ticks late.
// ---------------------------------------------------------------------------
constexpr int ENC_LDS = 2 * 16 * 4 * 64 * 16 + 4 * 64 * 16 * 4 + 256;  // 147712

__global__ void __launch_bounds__(256, 1) k_enc(
    const int* __restrict__ text,
    const float* __restrict__ WihF, const float* __restrict__ WhhF, const float* __restrict__ bF,
    const float* __restrict__ WihB, const float* __restrict__ WhhB, const float* __restrict__ bB,
    const unsigned short* __restrict__ emb_h, const unsigned short* __restrict__ emb_l,
    const float* __restrict__ sp,
    unsigned short* hencfh, unsigned short* hencfl,
    unsigned short* ench, unsigned short* encl,
    int* tagHE, int* warE) {
  extern __shared__ char lds[];
  unsigned short* Wh = (unsigned short*)lds;
  unsigned short* Wl = Wh + 16 * 4 * 64 * 8;
  float* G = (float*)(lds + 2 * 16 * 4 * 64 * 16);
  float* bias = G + 4 * 64 * 16;

  const int wg = blockIdx.x;
  const int dir = wg >> 4;
  const int cg = wg & 15;
  const int jhb = cg * 16;
  const int tid = threadIdx.x;
  const int wv = tid >> 6, ln = tid & 63, lg = ln >> 4, lr = ln & 15;

  const float* Wih = dir ? WihB : WihF;
  const float* Whh = dir ? WhhB : WhhF;
  const float* bb = dir ? bB : bF;

  for (int s = tid; s < 16 * 4 * 64; s += 256) {
    int kb = s >> 8, g = (s >> 6) & 3, l = s & 63;
    int R = g * Hd_ + jhb + (l & 15);
    int k0 = kb * 32 + (l >> 4) * 8;
    const float* src = (k0 < E_) ? (Wih + (size_t)R * E_ + k0) : (Whh + (size_t)R * Hd_ + (k0 - E_));
    bf16x8 vh, vl;
#pragma unroll
    for (int j = 0; j < 8; ++j) {
      unsigned short a, b; split2(src[j], a, b);
      vh[j] = (short)a; vl[j] = (short)b;
    }
    *(bf16x8*)(Wh + (size_t)s * 8) = vh;
    *(bf16x8*)(Wl + (size_t)s * 8) = vl;
  }
  if (tid < 64) bias[tid] = bb[(tid >> 4) * Hd_ + jhb + (tid & 15)];

  const int eb = tid >> 2, ej0 = (tid & 3) * 4;
  float c4[4] = {0.f, 0.f, 0.f, 0.f};
  float spv[4];
#pragma unroll
  for (int q = 0; q < 4; ++q) spv[q] = sp[eb * H_ + dir * Hd_ + jhb + ej0 + q];

  const int jh = jhb + ej0;
  const size_t fro = ((size_t)((jh >> 5) * 4 + (eb >> 4)) * 64 +
                      (((jh >> 3) & 3) * 16 + (eb & 15))) * 8 + (jh & 7);

  __syncthreads();

  for (int t = 0; t < L_; ++t) {
    const int tpos = dir ? (L_ - 1 - t) : t;
    const unsigned short* hsh = hencfh + ((size_t)(((t - 1) & 3) * 2 + dir)) * 16384;
    const unsigned short* hsl = hencfl + ((size_t)(((t - 1) & 3) * 2 + dir)) * 16384;
    unsigned short* hdh = hencfh + ((size_t)((t & 3) * 2 + dir)) * 16384;
    unsigned short* hdl = hencfl + ((size_t)((t & 3) * 2 + dir)) * 16384;

    for (int i = tid; i < 4096; i += 256) G[i] = bias[((i >> 10) << 4) + (i & 15)];

    int tix[4];
#pragma unroll
    for (int m = 0; m < 4; ++m) tix[m] = text[(16 * m + lr) * L_ + tpos];

    f32x4 acc[4][4];
#pragma unroll
    for (int g = 0; g < 4; ++g)
#pragma unroll
      for (int m = 0; m < 4; ++m) acc[g][m] = (f32x4){0.f, 0.f, 0.f, 0.f};

    auto issueE = [&](int j, bf16x8 (&S)[8]) {
      const int kb = wv + 4 * j;
      if (kb < 8) {
        const int k0 = kb * 32 + lg * 8;
#pragma unroll
        for (int m = 0; m < 4; ++m) {
          ldg16(S[m],     emb_h + (size_t)tix[m] * E_ + k0);
          ldg16(S[4 + m], emb_l + (size_t)tix[m] * E_ + k0);
        }
      } else {
        const unsigned short* ph = hsh + ((size_t)((kb - 8) * 4) * 64 + ln) * 8;
        const unsigned short* pl = hsl + ((size_t)((kb - 8) * 4) * 64 + ln) * 8;
#pragma unroll
        for (int m = 0; m < 4; ++m) { ldc16(S[m], ph + m * 512); ldc16(S[4 + m], pl + m * 512); }
      }
    };
    auto MFE = [&](int kb, bf16x8 (&S)[8]) {
#pragma unroll
      for (int g = 0; g < 4; ++g) {
        bf16x8 bh = *(bf16x8*)(Wh + ((size_t)(kb * 4 + g) * 64 + ln) * 8);
        bf16x8 bl = *(bf16x8*)(Wl + ((size_t)(kb * 4 + g) * 64 + ln) * 8);
#pragma unroll
        for (int m = 0; m < 4; ++m) {
          acc[g][m] = mfma16(S[m],     bh, acc[g][m]);
          acc[g][m] = mfma16(S[4 + m], bh, acc[g][m]);
          acc[g][m] = mfma16(S[m],     bl, acc[g][m]);
        }
      }
    };

    bf16x8 S0[8], S1[8], S2[8];
    issueE(0, S0);                      // embed (tag-free)
    issueE(1, S1);                      // embed (tag-free)
    tagwait1(tagHE, dir * 16 + (ln & 15), t);   // h[t-1] present (drains vmcnt)
    issueE(2, S2);                      // h
    MFE(wv, S0);
    issueE(3, S0);                      // h
    MFE(wv + 4, S1);
    WAITV(8);  MFE(wv + 8, S2);
    WAITV(0);  MFE(wv + 12, S0);

    __syncthreads();
#pragma unroll
    for (int g = 0; g < 4; ++g)
#pragma unroll
      for (int m = 0; m < 4; ++m)
#pragma unroll
        for (int r = 0; r < 4; ++r)
          atomicAdd(&G[(g * 64 + 16 * m + 4 * lg + r) * 16 + lr], acc[g][m][r]);
    __syncthreads();

    if (t >= 3) warwait(warE + dir * 16, 16 * (t - 2));

    {
      u16x4 hvh, hvl, ovh, ovl;
#pragma unroll
      for (int q = 0; q < 4; ++q) {
        int jj = ej0 + q;
        float gi = G[(0 * 64 + eb) * 16 + jj];
        float gf = G[(1 * 64 + eb) * 16 + jj];
        float gg = G[(2 * 64 + eb) * 16 + jj];
        float go = G[(3 * 64 + eb) * 16 + jj];
        float cn = sigm(gf) * c4[q] + sigm(gi) * tanh_(gg);
        c4[q] = cn;
        float h = sigm(go) * tanh_(cn);
        unsigned short a, b; split2(h, a, b);
        hvh[q] = a; hvl[q] = b;
        float o = h + spv[q];
        split2(o, a, b);
        ovh[q] = a; ovl[q] = b;
      }
      st8c(hdh + fro, hvh);
      st8c(hdl + fro, hvl);
      *(u16x4*)(ench + ((size_t)tpos * B_ + eb) * H_ + dir * Hd_ + jhb + ej0) = ovh;
      *(u16x4*)(encl + ((size_t)tpos * B_ + eb) * H_ + dir * Hd_ + jhb + ej0) = ovl;
    }
    VM_DRAIN();
    __syncthreads();
    if (tid == 0) {
      sti4c(&tagHE[dir * 16 + cg], t + 1);
      __hip_atomic_fetch_add(&warE[dir * 16], 1, __ATOMIC_RELAXED, __HIP_MEMORY_SCOPE_AGENT);
    }
  }
}

// ---------------------------------------------------------------------------
// Decoder: 128 WGs (64/layer, 8 cols each), pipelined by one tick.
// h rings: 4 slots x [16kb][4m][64][8]. tagH0[wg]=tau+1 (h0[tau]);
// tagH1[wg-64]=tau (h1[tau-1]). WAR via warD, waited 3 ticks late.
// ---------------------------------------------------------------------------
constexpr int DEC_LDS = 2 * 35 * 2 * 64 * 16 + 4 * 64 * 8 * 4 + 128;  // 151680

__global__ void __launch_bounds__(256, 1) k_dec(
    const float* __restrict__ Wih0, const float* __restrict__ Whh0, const float* __restrict__ b0,
    const float* __restrict__ Wih1, const float* __restrict__ Whh1, const float* __restrict__ b1,
    const unsigned short* __restrict__ ench, const unsigned short* __restrict__ encl,
    const unsigned short* __restrict__ melh, const unsigned short* __restrict__ mell,
    unsigned short* h0fh, unsigned short* h0fl,
    unsigned short* h1fh, unsigned short* h1fl,
    unsigned short* h2_full, int* tagH0, int* tagH1, int* warD) {
  extern __shared__ char lds[];
  const int wg = blockIdx.x;
  const int layer = wg >> 6;
  const int jcb = (wg & 63) * 8;
  const int tid = threadIdx.x, wv = tid >> 6, ln = tid & 63, lg = ln >> 4, lr = ln & 15;
  const int NKB = layer ? 32 : 35;
  unsigned short* Wh = (unsigned short*)lds;
  unsigned short* Wl = Wh + (size_t)NKB * 2 * 64 * 8;
  float* G = (float*)(lds + (size_t)2 * NKB * 2 * 64 * 16);
  float* bias = G + 4 * 64 * 8;

  if (layer == 0) {
    for (int s = tid; s < 35 * 2 * 64; s += 256) {
      int kb = s >> 7, st = (s >> 6) & 1, l = s & 63;
      int n = l & 15;
      int R = (2 * st + (n >> 3)) * H_ + jcb + (n & 7);
      int k0 = kb * 32 + (l >> 4) * 8;
      bf16x8 vh, vl;
      if (k0 < 96) {
#pragma unroll
        for (int j = 0; j < 8; ++j) {
          int c = k0 + j;
          float v = (c < 80) ? Wih0[(size_t)R * 592 + c] : 0.f;
          unsigned short a, b; split2(v, a, b);
          vh[j] = (short)a; vl[j] = (short)b;
        }
      } else if (k0 < 608) {
        const float* src = Wih0 + (size_t)R * 592 + (k0 - 16);
#pragma unroll
        for (int j = 0; j < 8; ++j) {
          unsigned short a, b; split2(src[j], a, b);
          vh[j] = (short)a; vl[j] = (short)b;
        }
      } else {
        const float* src = Whh0 + (size_t)R * H_ + (k0 - 608);
#pragma unroll
        for (int j = 0; j < 8; ++j) {
          unsigned short a, b; split2(src[j], a, b);
          vh[j] = (short)a; vl[j] = (short)b;
        }
      }
      *(bf16x8*)(Wh + (size_t)s * 8) = vh;
      *(bf16x8*)(Wl + (size_t)s * 8) = vl;
    }
    if (tid < 32) bias[tid] = b0[(tid >> 3) * H_ + jcb + (tid & 7)];
  } else {
    for (int s = tid; s < 32 * 2 * 64; s += 256) {
      int kb = s >> 7, st = (s >> 6) & 1, l = s & 63;
      int n = l & 15;
      int R = (2 * st + (n >> 3)) * H_ + jcb + (n & 7);
      int k0 = kb * 32 + (l >> 4) * 8;
      const float* src = (k0 < 512) ? (Wih1 + (size_t)R * H_ + k0) : (Whh1 + (size_t)R * H_ + (k0 - 512));
      bf16x8 vh, vl;
#pragma unroll
      for (int j = 0; j < 8; ++j) {
        unsigned short a, b; split2(src[j], a, b);
        vh[j] = (short)a; vl[j] = (short)b;
      }
      *(bf16x8*)(Wh + (size_t)s * 8) = vh;
      *(bf16x8*)(Wl + (size_t)s * 8) = vl;
    }
    if (tid < 32) bias[tid] = b1[(tid >> 3) * H_ + jcb + (tid & 7)];
  }

  const int ebd = tid & 63, cc0 = (tid >> 6) * 2;
  float c2[2] = {0.f, 0.f};
  const int j0w = jcb + cc0;
  const size_t frw = ((size_t)((j0w >> 5) * 4 + (ebd >> 4)) * 64 +
                      (((j0w >> 3) & 3) * 16 + (ebd & 15))) * 8 + (j0w & 7);
  __syncthreads();

  for (int tau = 0; tau <= T_; ++tau) {
    const bool active = (layer == 0) ? (tau < T_) : (tau >= 1);
    if (active) {
      const int t = (layer == 0) ? tau : tau - 1;
      for (int i = tid; i < 2048; i += 256) G[i] = bias[((i >> 9) << 3) + (i & 7)];

      f32x4 acc[2][4];
#pragma unroll
      for (int st = 0; st < 2; ++st)
#pragma unroll
        for (int m = 0; m < 4; ++m) acc[st][m] = (f32x4){0.f, 0.f, 0.f, 0.f};

      auto MF = [&](int kb, bf16x8 (&S)[8]) {
#pragma unroll
        for (int st = 0; st < 2; ++st) {
          bf16x8 bh = *(bf16x8*)(Wh + ((size_t)(kb * 2 + st) * 64 + ln) * 8);
          bf16x8 bl = *(bf16x8*)(Wl + ((size_t)(kb * 2 + st) * 64 + ln) * 8);
#pragma unroll
          for (int m = 0; m < 4; ++m) {
            acc[st][m] = mfma16(S[m],     bh, acc[st][m]);
            acc[st][m] = mfma16(S[4 + m], bh, acc[st][m]);
            acc[st][m] = mfma16(S[m],     bl, acc[st][m]);
          }
        }
      };

      bf16x8 S0[8], S1[8], S2[8], S3[8];

      if (layer == 0) {
        const int tq = t & (L_ - 1);
        const unsigned short* p0h = h0fh + (size_t)((tau - 1) & 3) * 32768;
        const unsigned short* p0l = h0fl + (size_t)((tau - 1) & 3) * 32768;
        auto issueL0 = [&](int j, bf16x8 (&S)[8]) {
          const int kb = wv + 4 * j;
          const int k0 = kb * 32 + lg * 8;
          if (kb < 3) {
#pragma unroll
            for (int m = 0; m < 4; ++m) {
              ldg16(S[m],     melh + ((size_t)t * B_ + 16 * m + lr) * 96 + k0);
              ldg16(S[4 + m], mell + ((size_t)t * B_ + 16 * m + lr) * 96 + k0);
            }
          } else if (kb < 19) {
            const int k = k0 - 96;
#pragma unroll
            for (int m = 0; m < 4; ++m) {
              ldg16(S[m],     ench + ((size_t)tq * B_ + 16 * m + lr) * H_ + k);
              ldg16(S[4 + m], encl + ((size_t)tq * B_ + 16 * m + lr) * H_ + k);
            }
          } else {
            const unsigned short* ph = p0h + ((size_t)((kb - 19) * 4) * 64 + ln) * 8;
            const unsigned short* pl = p0l + ((size_t)((kb - 19) * 4) * 64 + ln) * 8;
#pragma unroll
            for (int m = 0; m < 4; ++m) { ldc16(S[m], ph + m * 512); ldc16(S[4 + m], pl + m * 512); }
          }
        };
        // j0..j2 are mel/query (kb <= 11 for all wv): issue before tag poll
        issueL0(0, S0); issueL0(1, S1); issueL0(2, S2);
        tagwait1(tagH0, ln, tau);   // h0[tau-1] present (drains vmcnt)
        MF(wv, S0);      issueL0(3, S0);
        MF(wv + 4, S1);  issueL0(4, S1);
        MF(wv + 8, S2);  issueL0(5, S2);
        if (wv < 3) {
          constexpr int N = 9;
#pragma unroll
          for (int j = 3; j < N; ++j) {
            if (j + 2 < N) { WAITV(16); } else if (j + 1 < N) { WAITV(8); } else { WAITV(0); }
            const int kb = wv + 4 * j;
            if (j % 3 == 0)      { MF(kb, S0); if (j + 3 < N) issueL0(j + 3, S0); }
            else if (j % 3 == 1) { MF(kb, S1); if (j + 3 < N) issueL0(j + 3, S1); }
            else                 { MF(kb, S2); if (j + 3 < N) issueL0(j + 3, S2); }
          }
        } else {
          constexpr int N = 8;
#pragma unroll
          for (int j = 3; j < N; ++j) {
            if (j + 2 < N) { WAITV(16); } else if (j + 1 < N) { WAITV(8); } else { WAITV(0); }
            const int kb = wv + 4 * j;
            if (j % 3 == 0)      { MF(kb, S0); if (j + 3 < N) issueL0(j + 3, S0); }
            else if (j % 3 == 1) { MF(kb, S1); if (j + 3 < N) issueL0(j + 3, S1); }
            else                 { MF(kb, S2); if (j + 3 < N) issueL0(j + 3, S2); }
          }
        }
      } else {
        const unsigned short* q0h = h0fh + (size_t)((tau - 1) & 3) * 32768;
        const unsigned short* q0l = h0fl + (size_t)((tau - 1) & 3) * 32768;
        const unsigned short* q1h = h1fh + (size_t)((tau - 2) & 3) * 32768;
        const unsigned short* q1l = h1fl + (size_t)((tau - 2) & 3) * 32768;
        auto issueL1 = [&](int j, bf16x8 (&S)[8]) {
          const int kb = wv + 4 * j;
          const unsigned short* ph = (kb < 16) ? (q0h + ((size_t)(kb * 4) * 64 + ln) * 8)
                                               : (q1h + ((size_t)((kb - 16) * 4) * 64 + ln) * 8);
          const unsigned short* pl = (kb < 16) ? (q0l + ((size_t)(kb * 4) * 64 + ln) * 8)
                                               : (q1l + ((size_t)((kb - 16) * 4) * 64 + ln) * 8);
#pragma unroll
          for (int m = 0; m < 4; ++m) { ldc16(S[m], ph + m * 512); ldc16(S[4 + m], pl + m * 512); }
        };
        tagwait2(tagH0, tagH1, ln, tau, tau - 1);   // h0[tau-1] & h1[tau-2]
        issueL1(0, S0); issueL1(1, S1); issueL1(2, S2); issueL1(3, S3);
#pragma unroll
        for (int j = 0; j < 8; ++j) {
          if (j + 3 < 8) { WAITV(24); } else if (j + 2 < 8) { WAITV(16); }
          else if (j + 1 < 8) { WAITV(8); } else { WAITV(0); }
          const int kb = wv + 4 * j;
          if ((j & 3) == 0)      { MF(kb, S0); if (j + 4 < 8) issueL1(j + 4, S0); }
          else if ((j & 3) == 1) { MF(kb, S1); if (j + 4 < 8) issueL1(j + 4, S1); }
          else if ((j & 3) == 2) { MF(kb, S2); if (j + 4 < 8) issueL1(j + 4, S2); }
          else                   { MF(kb, S3); if (j + 4 < 8) issueL1(j + 4, S3); }
        }
      }

      __syncthreads();
#pragma unroll
      for (int st = 0; st < 2; ++st)
#pragma unroll
        for (int m = 0; m < 4; ++m)
#pragma unroll
          for (int r = 0; r < 4; ++r) {
            int g = 2 * st + (lr >> 3), col = lr & 7;
            atomicAdd(&G[(g * 64 + 16 * m + 4 * lg + r) * 8 + col], acc[st][m][r]);
          }
      __syncthreads();

      if (tau >= 3) warwait(warD, 128 * (tau - 2));

      {
        unsigned short* dh = layer ? (h1fh + (size_t)((tau - 1) & 3) * 32768)
                                   : (h0fh + (size_t)(tau & 3) * 32768);
        unsigned short* dl = layer ? (h1fl + (size_t)((tau - 1) & 3) * 32768)
                                   : (h0fl + (size_t)(tau & 3) * 32768);
        unsigned short hh[2], hl[2];
#pragma unroll
        for (int q = 0; q < 2; ++q) {
          int c = cc0 + q;
          float gi = G[(0 * 64 + ebd) * 8 + c];
          float gf = G[(1 * 64 + ebd) * 8 + c];
          float gg = G[(2 * 64 + ebd) * 8 + c];
          float go = G[(3 * 64 + ebd) * 8 + c];
          float cn = sigm(gf) * c2[q] + sigm(gi) * tanh_(gg);
          c2[q] = cn;
          float h = sigm(go) * tanh_(cn);
          split2(h, hh[q], hl[q]);
        }
        unsigned ph = (unsigned)hh[0] | ((unsigned)hh[1] << 16);
        unsigned pl = (unsigned)hl[0] | ((unsigned)hl[1] << 16);
        st4c(dh + frw, ph);
        st4c(dl + frw, pl);
        if (layer) *(unsigned*)(h2_full + ((size_t)t * B_ + ebd) * H_ + jcb + cc0) = ph;
      }
      VM_DRAIN();
      __syncthreads();
      if (tid == 0) {
        if (layer == 0) sti4c(&tagH0[wg], tau + 1);
        else            sti4c(&tagH1[wg - 64], tau);
        __hip_atomic_fetch_add(warD, 1, __ATOMIC_RELAXED, __HIP_MEMORY_SCOPE_AGENT);
      }
    } else {
      if (tid == 0)
        __hip_atomic_fetch_add(warD, 1, __ATOMIC_RELAXED, __HIP_MEMORY_SCOPE_AGENT);
    }
  }
}

// ---------------------------------------------------------------------------
constexpr int MLP_LDS = 64 * 1024;

__global__ void __launch_bounds__(256) k_mlp(
    const unsigned short* __restrict__ h2_full,
    const unsigned short* __restrict__ w1_bf, const unsigned short* __restrict__ w2_bf,
    const float* __restrict__ mb1, const float* __restrict__ mb2,
    const float* __restrict__ stW, const float* __restrict__ stb, float* out) {
  extern __shared__ char lds[];
  const int t = blockIdx.x;
  const int tid = threadIdx.x, wv = tid >> 6, ln = tid & 63, lg = ln >> 4, lr = ln & 15;
  const unsigned short* A = h2_full + (size_t)t * B_ * H_;

  for (int half = 0; half < 2; ++half) {
    const int nb = wv * 8 + half * 4;
    f32x4 acc[4][4];
#pragma unroll
    for (int nn = 0; nn < 4; ++nn) {
      float bv = mb1[(nb + nn) * 16 + lr];
#pragma unroll
      for (int m = 0; m < 4; ++m) acc[m][nn] = (f32x4){bv, bv, bv, bv};
    }
    for (int kb = 0; kb < 16; ++kb) {
      int k0 = kb * 32 + lg * 8;
      bf16x8 afr[4], bfr[4];
#pragma unroll
      for (int m = 0; m < 4; ++m) afr[m] = *(const bf16x8*)(A + (size_t)(16 * m + lr) * H_ + k0);
#pragma unroll
      for (int nn = 0; nn < 4; ++nn) bfr[nn] = *(const bf16x8*)(w1_bf + (size_t)((nb + nn) * 16 + lr) * H_ + k0);
#pragma unroll
      for (int m = 0; m < 4; ++m)
#pragma unroll
        for (int nn = 0; nn < 4; ++nn) acc[m][nn] = mfma16(afr[m], bfr[nn], acc[m][nn]);
    }
#pragma unroll
    for (int m = 0; m < 4; ++m)
#pragma unroll
      for (int nn = 0; nn < 4; ++nn)
#pragma unroll
        for (int r = 0; r < 4; ++r) {
          int row = 16 * m + 4 * lg + r, col = (nb + nn) * 16 + lr;
          *(unsigned short*)(lds + row * 1024 + ((col * 2) ^ ((row & 7) << 4))) =
              f2bs(fmaxf(acc[m][nn][r], 0.f));
        }
  }
  __syncthreads();

  {
    f32x4 acc2[5];
#pragma unroll
    for (int n = 0; n < 5; ++n) {
      float bv = mb2[n * 16 + lr];
      acc2[n] = (f32x4){bv, bv, bv, bv};
    }
    for (int kb = 0; kb < 16; ++kb) {
      int k0 = kb * 32 + lg * 8;
      int row = 16 * wv + lr;
      bf16x8 afr = *(bf16x8*)(lds + row * 1024 + ((k0 * 2) ^ ((row & 7) << 4)));
#pragma unroll
      for (int n = 0; n < 5; ++n) {
        bf16x8 bfr = *(const bf16x8*)(w2_bf + (size_t)(n * 16 + lr) * H_ + k0);
        acc2[n] = mfma16(afr, bfr, acc2[n]);
      }
    }
#pragma unroll
    for (int n = 0; n < 5; ++n)
#pragma unroll
      for (int r = 0; r < 4; ++r) {
        int b = 16 * wv + 4 * lg + r;
        out[((size_t)b * T_ + t) * M_ + n * 16 + lr] = acc2[n][r];
      }
  }

  if (tid < 64) {
    int b = tid;
    float s = stb[0];
    const unsigned short* hp = A + (size_t)b * H_;
    for (int k = 0; k < H_; ++k) s += b2f(hp[k]) * stW[k];
    out[(size_t)B_ * T_ * M_ + (size_t)b * T_ + t] = s;
  }
}

// ---------------------------------------------------------------------------
extern "C" void kernel_launch(void* const* d_in, const int* in_sizes, int n_in,
                              void* d_out, int out_size, void* d_ws, size_t ws_size,
                              hipStream_t stream) {
  (void)in_sizes; (void)n_in; (void)out_size; (void)ws_size;
  const int* text = (const int*)d_in[0];
  const float* spk = (const float*)d_in[1];
  const float* tmel = (const float*)d_in[2];
  const float* embed = (const float*)d_in[3];
  const float* eWihF = (const float*)d_in[4];
  const float* eWhhF = (const float*)d_in[5];
  const float* ebF = (const float*)d_in[6];
  const float* eWihB = (const float*)d_in[7];
  const float* eWhhB = (const float*)d_in[8];
  const float* ebB = (const float*)d_in[9];
  const float* spW1 = (const float*)d_in[10];
  const float* spb1 = (const float*)d_in[11];
  const float* spW2 = (const float*)d_in[12];
  const float* spb2 = (const float*)d_in[13];
  const float* dWih0 = (const float*)d_in[14];
  const float* dWhh0 = (const float*)d_in[15];
  const float* db0 = (const float*)d_in[16];
  const float* dWih1 = (const float*)d_in[17];
  const float* dWhh1 = (const float*)d_in[18];
  const float* db1 = (const float*)d_in[19];
  const float* mW1 = (const float*)d_in[20];
  const float* mb1 = (const float*)d_in[21];
  const float* mW2 = (const float*)d_in[22];
  const float* mb2 = (const float*)d_in[23];
  const float* stW = (const float*)d_in[24];
  const float* stb = (const float*)d_in[25];
  float* out = (float*)d_out;

  char* base = (char*)d_ws;
  size_t off = 0;
  auto carve = [&](size_t bytes) -> void* {
    void* p = base + off;
    off += (bytes + 255) & ~(size_t)255;
    return p;
  };
  // --- state region (zeroed each call) ---
  int* tagH0 = (int*)carve(64 * 4);
  int* tagH1 = (int*)carve(64 * 4);
  int* tagHE = (int*)carve(32 * 4);
  int* warD  = (int*)carve(16 * 4);
  int* warE  = (int*)carve(32 * 4);
  unsigned short* h0fh = (unsigned short*)carve((size_t)4 * 32768 * 2);   // 4 slots
  unsigned short* h0fl = (unsigned short*)carve((size_t)4 * 32768 * 2);
  unsigned short* h1fh = (unsigned short*)carve((size_t)4 * 32768 * 2);
  unsigned short* h1fl = (unsigned short*)carve((size_t)4 * 32768 * 2);
  unsigned short* hencfh = (unsigned short*)carve((size_t)8 * 16384 * 2); // 4 slots x 2 dir
  unsigned short* hencfl = (unsigned short*)carve((size_t)8 * 16384 * 2);
  const size_t state_bytes = off;
  // --- write-before-read buffers ---
  float* sp = (float*)carve((size_t)B_ * H_ * 4);
  unsigned short* emb_h = (unsigned short*)carve((size_t)256 * 256 * 2);
  unsigned short* emb_l = (unsigned short*)carve((size_t)256 * 256 * 2);
  unsigned short* mel_h = (unsigned short*)carve((size_t)T_ * B_ * 96 * 2);
  unsigned short* mel_l = (unsigned short*)carve((size_t)T_ * B_ * 96 * 2);
  unsigned short* w1_bf = (unsigned short*)carve((size_t)512 * 512 * 2);
  unsigned short* w2_bf = (unsigned short*)carve((size_t)80 * 512 * 2);
  unsigned short* ench = (unsigned short*)carve((size_t)L_ * B_ * H_ * 2);   // t-major
  unsigned short* encl = (unsigned short*)carve((size_t)L_ * B_ * H_ * 2);
  unsigned short* h2_full = (unsigned short*)carve((size_t)T_ * B_ * H_ * 2);

  hipMemsetAsync(d_ws, 0, state_bytes, stream);

  hipFuncSetAttribute((const void*)k_enc, hipFuncAttributeMaxDynamicSharedMemorySize, ENC_LDS);
  hipFuncSetAttribute((const void*)k_dec, hipFuncAttributeMaxDynamicSharedMemorySize, DEC_LDS);
  hipFuncSetAttribute((const void*)k_mlp, hipFuncAttributeMaxDynamicSharedMemorySize, MLP_LDS);

  k_prep<<<2048, 256, 0, stream>>>(embed, tmel, mW1, mW2, emb_h, emb_l, mel_h, mel_l, w1_bf, w2_bf);
  k_sp<<<64, 512, 0, stream>>>(spk, spW1, spb1, spW2, spb2, sp);
  k_enc<<<32, 256, ENC_LDS, stream>>>(text, eWihF, eWhhF, ebF, eWihB, eWhhB, ebB,
                                      emb_h, emb_l, sp, hencfh, hencfl, ench, encl,
                                      tagHE, warE);
  k_dec<<<128, 256, DEC_LDS, stream>>>(dWih0, dWhh0, db0, dWih1, dWhh1, db1,
                                       ench, encl, mel_h, mel_l,
                                       h0fh, h0fl, h1fh, h1fl, h2_full,
                                       tagH0, tagH1, warD);
  k_mlp<<<1000, 256, MLP_LDS, stream>>>(h2_full, w1_bf, w2_bf, mb1, mb2, stW, stb, out);
}

// Round 15
// 33677.612 us; speedup vs baseline: 1.0754x; 1.0023x over previous
//
#include <hip/hip_runtime.h>
#include <cstdint>
#include <cstddef>

// ============================================================================
// VoiceCloningGenerator — R13 structure, DEVICE-scope (sc1-only) round.
// gfx950 SC[1:0]: 2=Device (sc1), 3=System (sc0+sc1). Cross-XCD coherence
// needs only Device scope; prior rounds used System scope on every h/tag op.
// ============================================================================

#define DEVI __device__ __forceinline__

typedef short bf16x8 __attribute__((ext_vector_type(8)));
typedef float f32x4 __attribute__((ext_vector_type(4)));
typedef unsigned short u16x4 __attribute__((ext_vector_type(4)));

constexpr int B_ = 64, L_ = 512, T_ = 1000, E_ = 256, H_ = 512, M_ = 80, S_ = 128, Hd_ = 256;

DEVI unsigned short f2bs(float f) {
  unsigned u = __builtin_bit_cast(unsigned, f);
  unsigned r = u + 0x7fffu + ((u >> 16) & 1u);
  return (unsigned short)(r >> 16);
}
DEVI float b2f(unsigned short s) { return __builtin_bit_cast(float, (unsigned)s << 16); }
DEVI void split2(float v, unsigned short& hi, unsigned short& lo) {
  hi = f2bs(v);
  lo = f2bs(v - b2f(hi));
}
DEVI float sigm(float x) { x = fminf(fmaxf(x, -30.f), 30.f); return 1.f / (1.f + __expf(-x)); }
DEVI float tanh_(float x) { x = fminf(fmaxf(x, -15.f), 15.f); float e = __expf(2.f * x); return (e - 1.f) / (e + 1.f); }

DEVI f32x4 mfma16(bf16x8 a, bf16x8 b, f32x4 c) {
  return __builtin_amdgcn_mfma_f32_16x16x32_bf16(a, b, c, 0, 0, 0);
}

// --- asm memory ops (device scope = sc1 only) -------------------------------
DEVI void ldg16(bf16x8& r, const unsigned short* p) {  // cached (L1/L2)
  asm volatile("global_load_dwordx4 %0, %1, off" : "=v"(r) : "v"(p));
}
DEVI void ldc16(bf16x8& r, const unsigned short* p) {  // device scope (IC)
  asm volatile("global_load_dwordx4 %0, %1, off sc1" : "=v"(r) : "v"(p));
}
DEVI void st4c(unsigned short* p, unsigned v) {
  asm volatile("global_store_dword %0, %1, off sc1" :: "v"(p), "v"(v));
}
DEVI void sti4c(int* p, int v) {
  asm volatile("global_store_dword %0, %1, off sc1" :: "v"(p), "v"(v));
}
DEVI void st8c(unsigned short* p, u16x4 v) {
  asm volatile("global_store_dwordx2 %0, %1, off sc1" :: "v"(p), "v"(v));
}
#define WAITV(N) do { asm volatile("s_waitcnt vmcnt(" #N ")" ::: "memory"); \
                      __builtin_amdgcn_sched_barrier(0); } while (0)
#define VM_DRAIN() WAITV(0)

DEVI void burn64() {
  float x = 0.5f;
#pragma unroll
  for (int i = 0; i < 64; ++i)
    asm volatile("v_fmac_f32 %0, %1, %1" : "+v"(x) : "v"(x));
  asm volatile("" :: "v"(x));
}

// --- tag / WAR waits (device-scope polls) ------------------------------------
DEVI void tagwait1(const int* tags, int idx, int thr) {
  const int* p = tags + idx;
  for (;;) {
    int v;
    asm volatile("global_load_dword %0, %1, off sc1" : "=v"(v) : "v"(p));
    burn64();
    asm volatile("s_waitcnt vmcnt(0)" ::: "memory");
    __builtin_amdgcn_sched_barrier(0);
    if (__all(v >= thr)) break;
  }
}
DEVI void tagwait2(const int* t0, const int* t1, int idx, int a, int b) {
  const int* p0 = t0 + idx;
  const int* p1 = t1 + idx;
  for (;;) {
    int v0, v1;
    asm volatile("global_load_dword %0, %1, off sc1" : "=v"(v0) : "v"(p0));
    asm volatile("global_load_dword %0, %1, off sc1" : "=v"(v1) : "v"(p1));
    burn64();
    asm volatile("s_waitcnt vmcnt(0)" ::: "memory");
    __builtin_amdgcn_sched_barrier(0);
    if (__all(v0 >= a) && __all(v1 >= b)) break;
  }
}
DEVI void warwait(const int* cnt, int thr) {
  for (;;) {
    int v;
    asm volatile("global_load_dword %0, %1, off sc1" : "=v"(v) : "v"(cnt));
    burn64();
    asm volatile("s_waitcnt vmcnt(0)" ::: "memory");
    __builtin_amdgcn_sched_barrier(0);
    if (v >= thr) break;
  }
}

// ---------------------------------------------------------------------------
__global__ void k_prep(const float* __restrict__ embed, const float* __restrict__ tmel,
                       const float* __restrict__ mw1, const float* __restrict__ mw2,
                       unsigned short* emb_h, unsigned short* emb_l,
                       unsigned short* mel_h, unsigned short* mel_l,
                       unsigned short* w1_bf, unsigned short* w2_bf) {
  const long long stride = (long long)gridDim.x * blockDim.x;
  const long long i0 = (long long)blockIdx.x * blockDim.x + threadIdx.x;
  for (long long i = i0; i < 256 * 256; i += stride) {
    unsigned short h, l; split2(embed[i], h, l);
    emb_h[i] = h; emb_l[i] = l;
  }
  for (long long i = i0; i < (long long)T_ * B_ * 96; i += stride) {
    int c = (int)(i % 96);
    long long tb = i / 96;
    int b = (int)(tb % B_);
    int t = (int)(tb / B_);
    float v = 0.f;
    if (t > 0 && c < 80) v = tmel[((long long)b * T_ + (t - 1)) * M_ + c];
    unsigned short h, l; split2(v, h, l);
    mel_h[i] = h; mel_l[i] = l;
  }
  for (long long i = i0; i < 512 * 512; i += stride) w1_bf[i] = f2bs(mw1[i]);
  for (long long i = i0; i < 80 * 512; i += stride) w2_bf[i] = f2bs(mw2[i]);
}

// ---------------------------------------------------------------------------
__global__ void __launch_bounds__(512) k_sp(const float* __restrict__ spk,
                                            const float* __restrict__ w1, const float* __restrict__ b1,
                                            const float* __restrict__ w2, const float* __restrict__ b2,
                                            float* sp) {
  __shared__ float t1[512];
  const int b = blockIdx.x, j = threadIdx.x;
  float a = b1[j];
  const float* sr = spk + b * S_;
  for (int k = 0; k < S_; ++k) a += sr[k] * w1[j * S_ + k];
  t1[j] = fmaxf(a, 0.f);
  __syncthreads();
  float a2 = b2[j];
  for (int k = 0; k < H_; ++k) a2 += t1[k] * w2[j * H_ + k];
  sp[b * H_ + j] = a2;
}

// ---------------------------------------------------------------------------
// Encoder: 2 dirs x 16 WGs x 16 cols, tagged dataflow, 4-slot rings.
// ---------------------------------------------------------------------------
constexpr int ENC_LDS = 2 * 16 * 4 * 64 * 16 + 4 * 64 * 16 * 4 + 256;  // 147712

__global__ void __launch_bounds__(256, 1) k_enc(
    const int* __restrict__ text,
    const float* __restrict__ WihF, const float* __restrict__ WhhF, const float* __restrict__ bF,
    const float* __restrict__ WihB, const float* __restrict__ WhhB, const float* __restrict__ bB,
    const unsigned short* __restrict__ emb_h, const unsigned short* __restrict__ emb_l,
    const float* __restrict__ sp,
    unsigned short* hencfh, unsigned short* hencfl,
    unsigned short* ench, unsigned short* encl,
    int* tagHE, int* warE) {
  extern __shared__ char lds[];
  unsigned short* Wh = (unsigned short*)lds;
  unsigned short* Wl = Wh + 16 * 4 * 64 * 8;
  float* G = (float*)(lds + 2 * 16 * 4 * 64 * 16);
  float* bias = G + 4 * 64 * 16;

  const int wg = blockIdx.x;
  const int dir = wg >> 4;
  const int cg = wg & 15;
  const int jhb = cg * 16;
  const int tid = threadIdx.x;
  const int wv = tid >> 6, ln = tid & 63, lg = ln >> 4, lr = ln & 15;

  const float* Wih = dir ? WihB : WihF;
  const float* Whh = dir ? WhhB : WhhF;
  const float* bb = dir ? bB : bF;

  for (int s = tid; s < 16 * 4 * 64; s += 256) {
    int kb = s >> 8, g = (s >> 6) & 3, l = s & 63;
    int R = g * Hd_ + jhb + (l & 15);
    int k0 = kb * 32 + (l >> 4) * 8;
    const float* src = (k0 < E_) ? (Wih + (size_t)R * E_ + k0) : (Whh + (size_t)R * Hd_ + (k0 - E_));
    bf16x8 vh, vl;
#pragma unroll
    for (int j = 0; j < 8; ++j) {
      unsigned short a, b; split2(src[j], a, b);
      vh[j] = (short)a; vl[j] = (short)b;
    }
    *(bf16x8*)(Wh + (size_t)s * 8) = vh;
    *(bf16x8*)(Wl + (size_t)s * 8) = vl;
  }
  if (tid < 64) bias[tid] = bb[(tid >> 4) * Hd_ + jhb + (tid & 15)];

  const int eb = tid >> 2, ej0 = (tid & 3) * 4;
  float c4[4] = {0.f, 0.f, 0.f, 0.f};
  float spv[4];
#pragma unroll
  for (int q = 0; q < 4; ++q) spv[q] = sp[eb * H_ + dir * Hd_ + jhb + ej0 + q];

  const int jh = jhb + ej0;
  const size_t fro = ((size_t)((jh >> 5) * 4 + (eb >> 4)) * 64 +
                      (((jh >> 3) & 3) * 16 + (eb & 15))) * 8 + (jh & 7);

  __syncthreads();

  for (int t = 0; t < L_; ++t) {
    const int tpos = dir ? (L_ - 1 - t) : t;
    const unsigned short* hsh = hencfh + ((size_t)(((t - 1) & 3) * 2 + dir)) * 16384;
    const unsigned short* hsl = hencfl + ((size_t)(((t - 1) & 3) * 2 + dir)) * 16384;
    unsigned short* hdh = hencfh + ((size_t)((t & 3) * 2 + dir)) * 16384;
    unsigned short* hdl = hencfl + ((size_t)((t & 3) * 2 + dir)) * 16384;

    for (int i = tid; i < 4096; i += 256) G[i] = bias[((i >> 10) << 4) + (i & 15)];

    int tix[4];
#pragma unroll
    for (int m = 0; m < 4; ++m) tix[m] = text[(16 * m + lr) * L_ + tpos];

    f32x4 acc[4][4];
#pragma unroll
    for (int g = 0; g < 4; ++g)
#pragma unroll
      for (int m = 0; m < 4; ++m) acc[g][m] = (f32x4){0.f, 0.f, 0.f, 0.f};

    auto issueE = [&](int j, bf16x8 (&S)[8]) {
      const int kb = wv + 4 * j;
      if (kb < 8) {
        const int k0 = kb * 32 + lg * 8;
#pragma unroll
        for (int m = 0; m < 4; ++m) {
          ldg16(S[m],     emb_h + (size_t)tix[m] * E_ + k0);
          ldg16(S[4 + m], emb_l + (size_t)tix[m] * E_ + k0);
        }
      } else {
        const unsigned short* ph = hsh + ((size_t)((kb - 8) * 4) * 64 + ln) * 8;
        const unsigned short* pl = hsl + ((size_t)((kb - 8) * 4) * 64 + ln) * 8;
#pragma unroll
        for (int m = 0; m < 4; ++m) { ldc16(S[m], ph + m * 512); ldc16(S[4 + m], pl + m * 512); }
      }
    };
    auto MFE = [&](int kb, bf16x8 (&S)[8]) {
#pragma unroll
      for (int g = 0; g < 4; ++g) {
        bf16x8 bh = *(bf16x8*)(Wh + ((size_t)(kb * 4 + g) * 64 + ln) * 8);
        bf16x8 bl = *(bf16x8*)(Wl + ((size_t)(kb * 4 + g) * 64 + ln) * 8);
#pragma unroll
        for (int m = 0; m < 4; ++m) {
          acc[g][m] = mfma16(S[m],     bh, acc[g][m]);
          acc[g][m] = mfma16(S[4 + m], bh, acc[g][m]);
          acc[g][m] = mfma16(S[m],     bl, acc[g][m]);
        }
      }
    };

    bf16x8 S0[8], S1[8], S2[8];
    issueE(0, S0);                      // embed (tag-free)
    issueE(1, S1);                      // embed (tag-free)
    tagwait1(tagHE, dir * 16 + (ln & 15), t);   // h[t-1] present (drains vmcnt)
    issueE(2, S2);                      // h
    MFE(wv, S0);
    issueE(3, S0);                      // h
    MFE(wv + 4, S1);
    WAITV(8);  MFE(wv + 8, S2);
    WAITV(0);  MFE(wv + 12, S0);

    __syncthreads();
#pragma unroll
    for (int g = 0; g < 4; ++g)
#pragma unroll
      for (int m = 0; m < 4; ++m)
#pragma unroll
        for (int r = 0; r < 4; ++r)
          atomicAdd(&G[(g * 64 + 16 * m + 4 * lg + r) * 16 + lr], acc[g][m][r]);
    __syncthreads();

    if (t >= 3) warwait(warE + dir * 16, 16 * (t - 2));

    {
      u16x4 hvh, hvl, ovh, ovl;
#pragma unroll
      for (int q = 0; q < 4; ++q) {
        int jj = ej0 + q;
        float gi = G[(0 * 64 + eb) * 16 + jj];
        float gf = G[(1 * 64 + eb) * 16 + jj];
        float gg = G[(2 * 64 + eb) * 16 + jj];
        float go = G[(3 * 64 + eb) * 16 + jj];
        float cn = sigm(gf) * c4[q] + sigm(gi) * tanh_(gg);
        c4[q] = cn;
        float h = sigm(go) * tanh_(cn);
        unsigned short a, b; split2(h, a, b);
        hvh[q] = a; hvl[q] = b;
        float o = h + spv[q];
        split2(o, a, b);
        ovh[q] = a; ovl[q] = b;
      }
      st8c(hdh + fro, hvh);
      st8c(hdl + fro, hvl);
      *(u16x4*)(ench + ((size_t)tpos * B_ + eb) * H_ + dir * Hd_ + jhb + ej0) = ovh;
      *(u16x4*)(encl + ((size_t)tpos * B_ + eb) * H_ + dir * Hd_ + jhb + ej0) = ovl;
    }
    VM_DRAIN();
    __syncthreads();
    if (tid == 0) {
      sti4c(&tagHE[dir * 16 + cg], t + 1);
      __hip_atomic_fetch_add(&warE[dir * 16], 1, __ATOMIC_RELAXED, __HIP_MEMORY_SCOPE_AGENT);
    }
  }
}

// ---------------------------------------------------------------------------
// Decoder: 128 WGs (64/layer, 8 cols each), tagged dataflow, 4-slot rings.
// ---------------------------------------------------------------------------
constexpr int DEC_LDS = 2 * 35 * 2 * 64 * 16 + 4 * 64 * 8 * 4 + 128;  // 151680

__global__ void __launch_bounds__(256, 1) k_dec(
    const float* __restrict__ Wih0, const float* __restrict__ Whh0, const float* __restrict__ b0,
    const float* __restrict__ Wih1, const float* __restrict__ Whh1, const float* __restrict__ b1,
    const unsigned short* __restrict__ ench, const unsigned short* __restrict__ encl,
    const unsigned short* __restrict__ melh, const unsigned short* __restrict__ mell,
    unsigned short* h0fh, unsigned short* h0fl,
    unsigned short* h1fh, unsigned short* h1fl,
    unsigned short* h2_full, int* tagH0, int* tagH1, int* warD) {
  extern __shared__ char lds[];
  const int wg = blockIdx.x;
  const int layer = wg >> 6;
  const int jcb = (wg & 63) * 8;
  const int tid = threadIdx.x, wv = tid >> 6, ln = tid & 63, lg = ln >> 4, lr = ln & 15;
  const int NKB = layer ? 32 : 35;
  unsigned short* Wh = (unsigned short*)lds;
  unsigned short* Wl = Wh + (size_t)NKB * 2 * 64 * 8;
  float* G = (float*)(lds + (size_t)2 * NKB * 2 * 64 * 16);
  float* bias = G + 4 * 64 * 8;

  if (layer == 0) {
    for (int s = tid; s < 35 * 2 * 64; s += 256) {
      int kb = s >> 7, st = (s >> 6) & 1, l = s & 63;
      int n = l & 15;
      int R = (2 * st + (n >> 3)) * H_ + jcb + (n & 7);
      int k0 = kb * 32 + (l >> 4) * 8;
      bf16x8 vh, vl;
      if (k0 < 96) {
#pragma unroll
        for (int j = 0; j < 8; ++j) {
          int c = k0 + j;
          float v = (c < 80) ? Wih0[(size_t)R * 592 + c] : 0.f;
          unsigned short a, b; split2(v, a, b);
          vh[j] = (short)a; vl[j] = (short)b;
        }
      } else if (k0 < 608) {
        const float* src = Wih0 + (size_t)R * 592 + (k0 - 16);
#pragma unroll
        for (int j = 0; j < 8; ++j) {
          unsigned short a, b; split2(src[j], a, b);
          vh[j] = (short)a; vl[j] = (short)b;
        }
      } else {
        const float* src = Whh0 + (size_t)R * H_ + (k0 - 608);
#pragma unroll
        for (int j = 0; j < 8; ++j) {
          unsigned short a, b; split2(src[j], a, b);
          vh[j] = (short)a; vl[j] = (short)b;
        }
      }
      *(bf16x8*)(Wh + (size_t)s * 8) = vh;
      *(bf16x8*)(Wl + (size_t)s * 8) = vl;
    }
    if (tid < 32) bias[tid] = b0[(tid >> 3) * H_ + jcb + (tid & 7)];
  } else {
    for (int s = tid; s < 32 * 2 * 64; s += 256) {
      int kb = s >> 7, st = (s >> 6) & 1, l = s & 63;
      int n = l & 15;
      int R = (2 * st + (n >> 3)) * H_ + jcb + (n & 7);
      int k0 = kb * 32 + (l >> 4) * 8;
      const float* src = (k0 < 512) ? (Wih1 + (size_t)R * H_ + k0) : (Whh1 + (size_t)R * H_ + (k0 - 512));
      bf16x8 vh, vl;
#pragma unroll
      for (int j = 0; j < 8; ++j) {
        unsigned short a, b; split2(src[j], a, b);
        vh[j] = (short)a; vl[j] = (short)b;
      }
      *(bf16x8*)(Wh + (size_t)s * 8) = vh;
      *(bf16x8*)(Wl + (size_t)s * 8) = vl;
    }
    if (tid < 32) bias[tid] = b1[(tid >> 3) * H_ + jcb + (tid & 7)];
  }

  const int ebd = tid & 63, cc0 = (tid >> 6) * 2;
  float c2[2] = {0.f, 0.f};
  const int j0w = jcb + cc0;
  const size_t frw = ((size_t)((j0w >> 5) * 4 + (ebd >> 4)) * 64 +
                      (((j0w >> 3) & 3) * 16 + (ebd & 15))) * 8 + (j0w & 7);
  __syncthreads();

  for (int tau = 0; tau <= T_; ++tau) {
    const bool active = (layer == 0) ? (tau < T_) : (tau >= 1);
    if (active) {
      const int t = (layer == 0) ? tau : tau - 1;
      for (int i = tid; i < 2048; i += 256) G[i] = bias[((i >> 9) << 3) + (i & 7)];

      f32x4 acc[2][4];
#pragma unroll
      for (int st = 0; st < 2; ++st)
#pragma unroll
        for (int m = 0; m < 4; ++m) acc[st][m] = (f32x4){0.f, 0.f, 0.f, 0.f};

      auto MF = [&](int kb, bf16x8 (&S)[8]) {
#pragma unroll
        for (int st = 0; st < 2; ++st) {
          bf16x8 bh = *(bf16x8*)(Wh + ((size_t)(kb * 2 + st) * 64 + ln) * 8);
          bf16x8 bl = *(bf16x8*)(Wl + ((size_t)(kb * 2 + st) * 64 + ln) * 8);
#pragma unroll
          for (int m = 0; m < 4; ++m) {
            acc[st][m] = mfma16(S[m],     bh, acc[st][m]);
            acc[st][m] = mfma16(S[4 + m], bh, acc[st][m]);
            acc[st][m] = mfma16(S[m],     bl, acc[st][m]);
          }
        }
      };

      bf16x8 S0[8], S1[8], S2[8], S3[8];

      if (layer == 0) {
        const int tq = t & (L_ - 1);
        const unsigned short* p0h = h0fh + (size_t)((tau - 1) & 3) * 32768;
        const unsigned short* p0l = h0fl + (size_t)((tau - 1) & 3) * 32768;
        auto issueL0 = [&](int j, bf16x8 (&S)[8]) {
          const int kb = wv + 4 * j;
          const int k0 = kb * 32 + lg * 8;
          if (kb < 3) {
#pragma unroll
            for (int m = 0; m < 4; ++m) {
              ldg16(S[m],     melh + ((size_t)t * B_ + 16 * m + lr) * 96 + k0);
              ldg16(S[4 + m], mell + ((size_t)t * B_ + 16 * m + lr) * 96 + k0);
            }
          } else if (kb < 19) {
            const int k = k0 - 96;
#pragma unroll
            for (int m = 0; m < 4; ++m) {
              ldg16(S[m],     ench + ((size_t)tq * B_ + 16 * m + lr) * H_ + k);
              ldg16(S[4 + m], encl + ((size_t)tq * B_ + 16 * m + lr) * H_ + k);
            }
          } else {
            const unsigned short* ph = p0h + ((size_t)((kb - 19) * 4) * 64 + ln) * 8;
            const unsigned short* pl = p0l + ((size_t)((kb - 19) * 4) * 64 + ln) * 8;
#pragma unroll
            for (int m = 0; m < 4; ++m) { ldc16(S[m], ph + m * 512); ldc16(S[4 + m], pl + m * 512); }
          }
        };
        issueL0(0, S0); issueL0(1, S1); issueL0(2, S2);
        tagwait1(tagH0, ln, tau);
        MF(wv, S0);      issueL0(3, S0);
        MF(wv + 4, S1);  issueL0(4, S1);
        MF(wv + 8, S2);  issueL0(5, S2);
        if (wv < 3) {
          constexpr int N = 9;
#pragma unroll
          for (int j = 3; j < N; ++j) {
            if (j + 2 < N) { WAITV(16); } else if (j + 1 < N) { WAITV(8); } else { WAITV(0); }
            const int kb = wv + 4 * j;
            if (j % 3 == 0)      { MF(kb, S0); if (j + 3 < N) issueL0(j + 3, S0); }
            else if (j % 3 == 1) { MF(kb, S1); if (j + 3 < N) issueL0(j + 3, S1); }
            else                 { MF(kb, S2); if (j + 3 < N) issueL0(j + 3, S2); }
          }
        } else {
          constexpr int N = 8;
#pragma unroll
          for (int j = 3; j < N; ++j) {
            if (j + 2 < N) { WAITV(16); } else if (j + 1 < N) { WAITV(8); } else { WAITV(0); }
            const int kb = wv + 4 * j;
            if (j % 3 == 0)      { MF(kb, S0); if (j + 3 < N) issueL0(j + 3, S0); }
            else if (j % 3 == 1) { MF(kb, S1); if (j + 3 < N) issueL0(j + 3, S1); }
            else                 { MF(kb, S2); if (j + 3 < N) issueL0(j + 3, S2); }
          }
        }
      } else {
        const unsigned short* q0h = h0fh + (size_t)((tau - 1) & 3) * 32768;
        const unsigned short* q0l = h0fl + (size_t)((tau - 1) & 3) * 32768;
        const unsigned short* q1h = h1fh + (size_t)((tau - 2) & 3) * 32768;
        const unsigned short* q1l = h1fl + (size_t)((tau - 2) & 3) * 32768;
        auto issueL1 = [&](int j, bf16x8 (&S)[8]) {
          const int kb = wv + 4 * j;
          const unsigned short* ph = (kb < 16) ? (q0h + ((size_t)(kb * 4) * 64 + ln) * 8)
                                               : (q1h + ((size_t)((kb - 16) * 4) * 64 + ln) * 8);
          const unsigned short* pl = (kb < 16) ? (q0l + ((size_t)(kb * 4) * 64 + ln) * 8)
                                               : (q1l + ((size_t)((kb - 16) * 4) * 64 + ln) * 8);
#pragma unroll
          for (int m = 0; m < 4; ++m) { ldc16(S[m], ph + m * 512); ldc16(S[4 + m], pl + m * 512); }
        };
        tagwait2(tagH0, tagH1, ln, tau, tau - 1);
        issueL1(0, S0); issueL1(1, S1); issueL1(2, S2); issueL1(3, S3);
#pragma unroll
        for (int j = 0; j < 8; ++j) {
          if (j + 3 < 8) { WAITV(24); } else if (j + 2 < 8) { WAITV(16); }
          else if (j + 1 < 8) { WAITV(8); } else { WAITV(0); }
          const int kb = wv + 4 * j;
          if ((j & 3) == 0)      { MF(kb, S0); if (j + 4 < 8) issueL1(j + 4, S0); }
          else if ((j & 3) == 1) { MF(kb, S1); if (j + 4 < 8) issueL1(j + 4, S1); }
          else if ((j & 3) == 2) { MF(kb, S2); if (j + 4 < 8) issueL1(j + 4, S2); }
          else                   { MF(kb, S3); if (j + 4 < 8) issueL1(j + 4, S3); }
        }
      }

      __syncthreads();
#pragma unroll
      for (int st = 0; st < 2; ++st)
#pragma unroll
        for (int m = 0; m < 4; ++m)
#pragma unroll
          for (int r = 0; r < 4; ++r) {
            int g = 2 * st + (lr >> 3), col = lr & 7;
            atomicAdd(&G[(g * 64 + 16 * m + 4 * lg + r) * 8 + col], acc[st][m][r]);
          }
      __syncthreads();

      if (tau >= 3) warwait(warD, 128 * (tau - 2));

      {
        unsigned short* dh = layer ? (h1fh + (size_t)((tau - 1) & 3) * 32768)
                                   : (h0fh + (size_t)(tau & 3) * 32768);
        unsigned short* dl = layer ? (h1fl + (size_t)((tau - 1) & 3) * 32768)
                                   : (h0fl + (size_t)(tau & 3) * 32768);
        unsigned short hh[2], hl[2];
#pragma unroll
        for (int q = 0; q < 2; ++q) {
          int c = cc0 + q;
          float gi = G[(0 * 64 + ebd) * 8 + c];
          float gf = G[(1 * 64 + ebd) * 8 + c];
          float gg = G[(2 * 64 + ebd) * 8 + c];
          float go = G[(3 * 64 + ebd) * 8 + c];
          float cn = sigm(gf) * c2[q] + sigm(gi) * tanh_(gg);
          c2[q] = cn;
          float h = sigm(go) * tanh_(cn);
          split2(h, hh[q], hl[q]);
        }
        unsigned ph = (unsigned)hh[0] | ((unsigned)hh[1] << 16);
        unsigned pl = (unsigned)hl[0] | ((unsigned)hl[1] << 16);
        st4c(dh + frw, ph);
        st4c(dl + frw, pl);
        if (layer) *(unsigned*)(h2_full + ((size_t)t * B_ + ebd) * H_ + jcb + cc0) = ph;
      }
      VM_DRAIN();
      __syncthreads();
      if (tid == 0) {
        if (layer == 0) sti4c(&tagH0[wg], tau + 1);
        else            sti4c(&tagH1[wg - 64], tau);
        __hip_atomic_fetch_add(warD, 1, __ATOMIC_RELAXED, __HIP_MEMORY_SCOPE_AGENT);
      }
    } else {
      if (tid == 0)
        __hip_atomic_fetch_add(warD, 1, __ATOMIC_RELAXED, __HIP_MEMORY_SCOPE_AGENT);
    }
  }
}

// ---------------------------------------------------------------------------
constexpr int MLP_LDS = 64 * 1024;

__global__ void __launch_bounds__(256) k_mlp(
    const unsigned short* __restrict__ h2_full,
    const unsigned short* __restrict__ w1_bf, const unsigned short* __restrict__ w2_bf,
    const float* __restrict__ mb1, const float* __restrict__ mb2,
    const float* __restrict__ stW, const float* __restrict__ stb, float* out) {
  extern __shared__ char lds[];
  const int t = blockIdx.x;
  const int tid = threadIdx.x, wv = tid >> 6, ln = tid & 63, lg = ln >> 4, lr = ln & 15;
  const unsigned short* A = h2_full + (size_t)t * B_ * H_;

  for (int half = 0; half < 2; ++half) {
    const int nb = wv * 8 + half * 4;
    f32x4 acc[4][4];
#pragma unroll
    for (int nn = 0; nn < 4; ++nn) {
      float bv = mb1[(nb + nn) * 16 + lr];
#pragma unroll
      for (int m = 0; m < 4; ++m) acc[m][nn] = (f32x4){bv, bv, bv, bv};
    }
    for (int kb = 0; kb < 16; ++kb) {
      int k0 = kb * 32 + lg * 8;
      bf16x8 afr[4], bfr[4];
#pragma unroll
      for (int m = 0; m < 4; ++m) afr[m] = *(const bf16x8*)(A + (size_t)(16 * m + lr) * H_ + k0);
#pragma unroll
      for (int nn = 0; nn < 4; ++nn) bfr[nn] = *(const bf16x8*)(w1_bf + (size_t)((nb + nn) * 16 + lr) * H_ + k0);
#pragma unroll
      for (int m = 0; m < 4; ++m)
#pragma unroll
        for (int nn = 0; nn < 4; ++nn) acc[m][nn] = mfma16(afr[m], bfr[nn], acc[m][nn]);
    }
#pragma unroll
    for (int m = 0; m < 4; ++m)
#pragma unroll
      for (int nn = 0; nn < 4; ++nn)
#pragma unroll
        for (int r = 0; r < 4; ++r) {
          int row = 16 * m + 4 * lg + r, col = (nb + nn) * 16 + lr;
          *(unsigned short*)(lds + row * 1024 + ((col * 2) ^ ((row & 7) << 4))) =
              f2bs(fmaxf(acc[m][nn][r], 0.f));
        }
  }
  __syncthreads();

  {
    f32x4 acc2[5];
#pragma unroll
    for (int n = 0; n < 5; ++n) {
      float bv = mb2[n * 16 + lr];
      acc2[n] = (f32x4){bv, bv, bv, bv};
    }
    for (int kb = 0; kb < 16; ++kb) {
      int k0 = kb * 32 + lg * 8;
      int row = 16 * wv + lr;
      bf16x8 afr = *(bf16x8*)(lds + row * 1024 + ((k0 * 2) ^ ((row & 7) << 4)));
#pragma unroll
      for (int n = 0; n < 5; ++n) {
        bf16x8 bfr = *(const bf16x8*)(w2_bf + (size_t)(n * 16 + lr) * H_ + k0);
        acc2[n] = mfma16(afr, bfr, acc2[n]);
      }
    }
#pragma unroll
    for (int n = 0; n < 5; ++n)
#pragma unroll
      for (int r = 0; r < 4; ++r) {
        int b = 16 * wv + 4 * lg + r;
        out[((size_t)b * T_ + t) * M_ + n * 16 + lr] = acc2[n][r];
      }
  }

  if (tid < 64) {
    int b = tid;
    float s = stb[0];
    const unsigned short* hp = A + (size_t)b * H_;
    for (int k = 0; k < H_; ++k) s += b2f(hp[k]) * stW[k];
    out[(size_t)B_ * T_ * M_ + (size_t)b * T_ + t] = s;
  }
}

// ---------------------------------------------------------------------------
extern "C" void kernel_launch(void* const* d_in, const int* in_sizes, int n_in,
                              void* d_out, int out_size, void* d_ws, size_t ws_size,
                              hipStream_t stream) {
  (void)in_sizes; (void)n_in; (void)out_size; (void)ws_size;
  const int* text = (const int*)d_in[0];
  const float* spk = (const float*)d_in[1];
  const float* tmel = (const float*)d_in[2];
  const float* embed = (const float*)d_in[3];
  const float* eWihF = (const float*)d_in[4];
  const float* eWhhF = (const float*)d_in[5];
  const float* ebF = (const float*)d_in[6];
  const float* eWihB = (const float*)d_in[7];
  const float* eWhhB = (const float*)d_in[8];
  const float* ebB = (const float*)d_in[9];
  const float* spW1 = (const float*)d_in[10];
  const float* spb1 = (const float*)d_in[11];
  const float* spW2 = (const float*)d_in[12];
  const float* spb2 = (const float*)d_in[13];
  const float* dWih0 = (const float*)d_in[14];
  const float* dWhh0 = (const float*)d_in[15];
  const float* db0 = (const float*)d_in[16];
  const float* dWih1 = (const float*)d_in[17];
  const float* dWhh1 = (const float*)d_in[18];
  const float* db1 = (const float*)d_in[19];
  const float* mW1 = (const float*)d_in[20];
  const float* mb1 = (const float*)d_in[21];
  const float* mW2 = (const float*)d_in[22];
  const float* mb2 = (const float*)d_in[23];
  const float* stW = (const float*)d_in[24];
  const float* stb = (const float*)d_in[25];
  float* out = (float*)d_out;

  char* base = (char*)d_ws;
  size_t off = 0;
  auto carve = [&](size_t bytes) -> void* {
    void* p = base + off;
    off += (bytes + 255) & ~(size_t)255;
    return p;
  };
  // --- state region (zeroed each call) ---
  int* tagH0 = (int*)carve(64 * 4);
  int* tagH1 = (int*)carve(64 * 4);
  int* tagHE = (int*)carve(32 * 4);
  int* warD  = (int*)carve(16 * 4);
  int* warE  = (int*)carve(32 * 4);
  unsigned short* h0fh = (unsigned short*)carve((size_t)4 * 32768 * 2);   // 4 slots
  unsigned short* h0fl = (unsigned short*)carve((size_t)4 * 32768 * 2);
  unsigned short* h1fh = (unsigned short*)carve((size_t)4 * 32768 * 2);
  unsigned short* h1fl = (unsigned short*)carve((size_t)4 * 32768 * 2);
  unsigned short* hencfh = (unsigned short*)carve((size_t)8 * 16384 * 2); // 4 slots x 2 dir
  unsigned short* hencfl = (unsigned short*)carve((size_t)8 * 16384 * 2);
  const size_t state_bytes = off;
  // --- write-before-read buffers ---
  float* sp = (float*)carve((size_t)B_ * H_ * 4);
  unsigned short* emb_h = (unsigned short*)carve((size_t)256 * 256 * 2);
  unsigned short* emb_l = (unsigned short*)carve((size_t)256 * 256 * 2);
  unsigned short* mel_h = (unsigned short*)carve((size_t)T_ * B_ * 96 * 2);
  unsigned short* mel_l = (unsigned short*)carve((size_t)T_ * B_ * 96 * 2);
  unsigned short* w1_bf = (unsigned short*)carve((size_t)512 * 512 * 2);
  unsigned short* w2_bf = (unsigned short*)carve((size_t)80 * 512 * 2);
  unsigned short* ench = (unsigned short*)carve((size_t)L_ * B_ * H_ * 2);   // t-major
  unsigned short* encl = (unsigned short*)carve((size_t)L_ * B_ * H_ * 2);
  unsigned short* h2_full = (unsigned short*)carve((size_t)T_ * B_ * H_ * 2);

  hipMemsetAsync(d_ws, 0, state_bytes, stream);

  hipFuncSetAttribute((const void*)k_enc, hipFuncAttributeMaxDynamicSharedMemorySize, ENC_LDS);
  hipFuncSetAttribute((const void*)k_dec, hipFuncAttributeMaxDynamicSharedMemorySize, DEC_LDS);
  hipFuncSetAttribute((const void*)k_mlp, hipFuncAttributeMaxDynamicSharedMemorySize, MLP_LDS);

  k_prep<<<2048, 256, 0, stream>>>(embed, tmel, mW1, mW2, emb_h, emb_l, mel_h, mel_l, w1_bf, w2_bf);
  k_sp<<<64, 512, 0, stream>>>(spk, spW1, spb1, spW2, spb2, sp);
  k_enc<<<32, 256, ENC_LDS, stream>>>(text, eWihF, eWhhF, ebF, eWihB, eWhhB, ebB,
                                      emb_h, emb_l, sp, hencfh, hencfl, ench, encl,
                                      tagHE, warE);
  k_dec<<<128, 256, DEC_LDS, stream>>>(dWih0, dWhh0, db0, dWih1, dWhh1, db1,
                                       ench, encl, mel_h, mel_l,
                                       h0fh, h0fl, h1fh, h1fl, h2_full,
                                       tagH0, tagH1, warD);
  k_mlp<<<1000, 256, MLP_LDS, stream>>>(h2_full, w1_bf, w2_bf, mb1, mb2, stW, stb, out);
}